// Round 11
// baseline (285.421 us; speedup 1.0000x reference)
//
#include <hip/hip_runtime.h>

// relationalGraphStack — round 10
// vs R9: k_gatherx+k_gemm1b+k_stats1 fused into k_layer1 (gather -> LDS tile ->
// MFMA K=576 -> h_pre, stats in epilogue): updx never touches HBM (saves 102MB
// round trip). k_norm killed: d accumulated alongside the weighted sums in the
// same unrolled loop (no serial pre-pass), result scaled by 1/d per segment.
// descT[s]=start|cnt<<20 gives g2 kernels one coalesced load per segment.

#define GATHER_GRID 2048
#define SCAN_CHUNK 4096
#define RED_BLOCKS 64
#define ZERO_BLOCKS 256
#define PACK_BLOCKS 16
#define XB_BLOCKS 64
#define COUNT_BLOCKS 2048
#define PLACE_BLOCKS 1024
#define L1_NODES 32

typedef short bf16x8 __attribute__((ext_vector_type(8)));
typedef float f32x4 __attribute__((ext_vector_type(4)));

static __device__ __forceinline__ float bf2f(unsigned short u) {
  return __uint_as_float(((unsigned)u) << 16);
}
static __device__ __forceinline__ unsigned short f2bf(float f) {
  unsigned u = __float_as_uint(f);
  u += 0x7FFFu + ((u >> 16) & 1u);  // round to nearest even
  return (unsigned short)(u >> 16);
}

// zero cnt + pack weights. wb1[j*576+k]: k<512 -> W_lin1[j*512+k], else W_self1.
// wb2[(s*64+j)*64+d]: s=0 W_lin2, s=1 W_self2.
__global__ void k_zeropack(int* __restrict__ cnt, int NR, int R,
                           const float* __restrict__ Wlin1, const float* __restrict__ Wself1,
                           const float* __restrict__ Wlin2, const float* __restrict__ Wself2,
                           unsigned short* __restrict__ wb1, unsigned short* __restrict__ wb2) {
  if (blockIdx.x < ZERO_BLOCKS) {
    int i = blockIdx.x * 256 + threadIdx.x;
    int stride = ZERO_BLOCKS * 256;
    for (int k = i; k < NR; k += stride) cnt[k] = 0;
  } else {
    int i = (blockIdx.x - ZERO_BLOCKS) * 256 + threadIdx.x;
    int stride = PACK_BLOCKS * 256;
    int KW = R * 64 + 64;                 // 576
    int n1 = 64 * KW;
    int n2 = 2 * 64 * 64;
    for (int t = i; t < n1 + n2; t += stride) {
      if (t < n1) {
        int j = t / KW, k = t - j * KW;
        float v = (k < R * 64) ? Wlin1[j * (R * 64) + k] : Wself1[j * 64 + (k - R * 64)];
        wb1[t] = f2bf(v);
      } else {
        int t2 = t - n1;
        int r = t2 >> 6, d = t2 & 63;
        float v = (r < 64) ? Wlin2[r * 64 + d] : Wself2[(r - 64) * 64 + d];
        wb2[t2] = f2bf(v);
      }
    }
  }
}

// blocks [0,XB_BLOCKS): x f32 -> xb bf16. blocks [XB_BLOCKS,...): count + rank tmp.
__global__ void k_countx(const int* __restrict__ node_out, const int* __restrict__ rel,
                         int* __restrict__ cnt, int* __restrict__ tmp, int E, int R,
                         const float4* __restrict__ xin, ushort4* __restrict__ xb, int n4) {
  if (blockIdx.x < XB_BLOCKS) {
    int i = blockIdx.x * 256 + threadIdx.x;
    int stride = XB_BLOCKS * 256;
    for (int k = i; k < n4; k += stride) {
      float4 v = xin[k];
      ushort4 o;
      o.x = f2bf(v.x); o.y = f2bf(v.y); o.z = f2bf(v.z); o.w = f2bf(v.w);
      xb[k] = o;
    }
  } else {
    int i = (blockIdx.x - XB_BLOCKS) * 256 + threadIdx.x;
    int stride = COUNT_BLOCKS * 256;
    for (int e = i; e < E; e += stride) {
      int seg = node_out[e] * R + rel[e];
      tmp[e] = atomicAdd(&cnt[seg], 1);
    }
  }
}

__global__ __launch_bounds__(256) void k_scan1(const int* __restrict__ cnt,
                                               int* __restrict__ bsum, int NR) {
  __shared__ int red[256];
  int tid = threadIdx.x;
  int base = blockIdx.x * SCAN_CHUNK;
  int s = 0;
  for (int i = tid; i < SCAN_CHUNK; i += 256) {
    int idx = base + i;
    if (idx < NR) s += cnt[idx];
  }
  red[tid] = s;
  __syncthreads();
  for (int off = 128; off > 0; off >>= 1) {
    if (tid < off) red[tid] += red[tid + off];
    __syncthreads();
  }
  if (tid == 0) bsum[blockIdx.x] = red[0];
}

__global__ void k_scan2(const int* __restrict__ bsum, int* __restrict__ bpre,
                        int* __restrict__ rowptr_end, int NB) {
  int lane = threadIdx.x;
  int carry = 0;
  for (int base = 0; base < NB; base += 64) {
    int i = base + lane;
    int v = (i < NB) ? bsum[i] : 0;
    int incl = v;
    #pragma unroll
    for (int off = 1; off < 64; off <<= 1) {
      int u = __shfl_up(incl, off);
      if (lane >= off) incl += u;
    }
    if (i < NB) bpre[i] = carry + incl - v;
    carry += __shfl(incl, 63);
  }
  if (lane == 0) *rowptr_end = carry;
}

// rowptr (n-major) + descT (s-major: descT[r*N+n] = start | cnt<<20)
__global__ __launch_bounds__(256) void k_scan3(const int* __restrict__ cnt,
                                               const int* __restrict__ bpre,
                                               int* __restrict__ rowptr,
                                               unsigned* __restrict__ descT,
                                               int NR, int R, int Nn) {
  __shared__ int wtot[4];
  int tid = threadIdx.x, lane = tid & 63, wid = tid >> 6;
  int base = blockIdx.x * SCAN_CHUNK + tid * 16;
  int v[16];
  int t = 0;
  #pragma unroll
  for (int i = 0; i < 16; i++) {
    int idx = base + i;
    v[i] = (idx < NR) ? cnt[idx] : 0;
    t += v[i];
  }
  int incl = t;
  #pragma unroll
  for (int off = 1; off < 64; off <<= 1) {
    int u = __shfl_up(incl, off);
    if (lane >= off) incl += u;
  }
  if (lane == 63) wtot[wid] = incl;
  __syncthreads();
  int woff = 0;
  for (int w = 0; w < wid; w++) woff += wtot[w];
  int start = bpre[blockIdx.x] + woff + incl - t;
  #pragma unroll
  for (int i = 0; i < 16; i++) {
    int idx = base + i;
    if (idx < NR) {
      rowptr[idx] = start;
      int n = (int)((unsigned)idx / (unsigned)R);
      int r = idx - n * R;
      descT[(size_t)r * Nn + n] = (unsigned)start | ((unsigned)v[i] << 20);
    }
    start += v[i];
  }
}

// placement, no atomics, 4B payload: ep4[rowptr[seg]+tmp[e]] = src | bf16(raw w)<<16
__global__ void k_place(const float* __restrict__ w, const int* __restrict__ node_out,
                        const int* __restrict__ node_in, const int* __restrict__ rel,
                        const int* __restrict__ rowptr, const int* __restrict__ tmp,
                        unsigned* __restrict__ ep4, int E, int R) {
  int i = blockIdx.x * blockDim.x + threadIdx.x;
  int stride = gridDim.x * blockDim.x;
  for (int e = i; e < E; e += stride) {
    int seg = node_out[e] * R + rel[e];
    int pos = rowptr[seg] + tmp[e];
    ep4[pos] = (unsigned)node_in[e] | ((unsigned)f2bf(w[e]) << 16);
  }
}

// Layer 1 fused: gather x per (node,r) -> LDS tile [32][512(+pad)], then
// MFMA K=576 (512 LDS + 64 xb) -> h_pre bf16; column stats in epilogue.
__global__ __launch_bounds__(256) void k_layer1(
    const int* __restrict__ rowptr, const unsigned* __restrict__ ep4,
    const unsigned short* __restrict__ xb, const unsigned short* __restrict__ wb1,
    unsigned short* __restrict__ h_pre, float* __restrict__ part, int M, int R) {
  __shared__ unsigned short tile[L1_NODES][520];   // 33,280 B
  int tid = threadIdx.x;
  int n0 = blockIdx.x * L1_NODES;
  {
    int gid = tid >> 4;      // 16 gather groups
    int l16 = tid & 15;
    int c0 = l16 * 4;
    int nseg = L1_NODES * R;
    for (int sl = gid; sl < nseg; sl += 16) {
      int nl = (int)((unsigned)sl / (unsigned)R);
      int r = sl - nl * R;
      int n = n0 + nl;
      float a0 = 0.f, a1 = 0.f, a2 = 0.f, a3 = 0.f, d = 0.f;
      if (n < M) {
        int seg = n * R + r;
        int k = rowptr[seg], k1 = rowptr[seg + 1];
        for (; k + 1 < k1; k += 2) {
          unsigned pA = ep4[k], pB = ep4[k + 1];
          ushort4 uA = *(const ushort4*)&xb[(size_t)(pA & 0xFFFFu) * 64 + c0];
          ushort4 uB = *(const ushort4*)&xb[(size_t)(pB & 0xFFFFu) * 64 + c0];
          float wA = bf2f((unsigned short)(pA >> 16));
          float wB = bf2f((unsigned short)(pB >> 16));
          d += wA + wB;
          a0 = fmaf(wA, bf2f(uA.x), a0); a1 = fmaf(wA, bf2f(uA.y), a1);
          a2 = fmaf(wA, bf2f(uA.z), a2); a3 = fmaf(wA, bf2f(uA.w), a3);
          a0 = fmaf(wB, bf2f(uB.x), a0); a1 = fmaf(wB, bf2f(uB.y), a1);
          a2 = fmaf(wB, bf2f(uB.z), a2); a3 = fmaf(wB, bf2f(uB.w), a3);
        }
        if (k < k1) {
          unsigned p = ep4[k];
          float w = bf2f((unsigned short)(p >> 16));
          ushort4 u = *(const ushort4*)&xb[(size_t)(p & 0xFFFFu) * 64 + c0];
          d += w;
          a0 = fmaf(w, bf2f(u.x), a0); a1 = fmaf(w, bf2f(u.y), a1);
          a2 = fmaf(w, bf2f(u.z), a2); a3 = fmaf(w, bf2f(u.w), a3);
        }
        if (d != 0.f) {
          float inv = 1.f / d;
          a0 *= inv; a1 *= inv; a2 *= inv; a3 *= inv;
        }
      }
      ushort4 o; o.x = f2bf(a0); o.y = f2bf(a1); o.z = f2bf(a2); o.w = f2bf(a3);
      *(ushort4*)&tile[nl][r * 64 + c0] = o;
    }
  }
  __syncthreads();
  // MFMA: 4 waves; wave w: rows (w&1)*16+[0,16), col-blocks nt = (w>>1)*2 + {0,1}
  int w = tid >> 6, lane = tid & 63;
  int rloc = (w & 1) * 16 + (lane & 15);
  int koff = 8 * (lane >> 4);
  const unsigned short* arow = &tile[rloc][koff];
  int gxrow = n0 + rloc; if (gxrow >= M) gxrow = M - 1;
  const unsigned short* aX = xb + (size_t)gxrow * 64 + koff;
  int ntbase = (w >> 1) * 2;
  const unsigned short* wr = wb1 + (size_t)(lane & 15) * 576 + koff;
  f32x4 acc[2] = {{0, 0, 0, 0}, {0, 0, 0, 0}};
  #pragma unroll
  for (int kk = 0; kk < 16; ++kk) {
    bf16x8 a = *(const bf16x8*)(arow + kk * 32);
    #pragma unroll
    for (int t = 0; t < 2; ++t) {
      bf16x8 b = *(const bf16x8*)(wr + (size_t)(ntbase + t) * 16 * 576 + kk * 32);
      acc[t] = __builtin_amdgcn_mfma_f32_16x16x32_bf16(a, b, acc[t], 0, 0, 0);
    }
  }
  #pragma unroll
  for (int kk = 0; kk < 2; ++kk) {
    bf16x8 a = *(const bf16x8*)(aX + kk * 32);
    #pragma unroll
    for (int t = 0; t < 2; ++t) {
      bf16x8 b = *(const bf16x8*)(wr + (size_t)(ntbase + t) * 16 * 576 + 512 + kk * 32);
      acc[t] = __builtin_amdgcn_mfma_f32_16x16x32_bf16(a, b, acc[t], 0, 0, 0);
    }
  }
  int cbase = lane & 15;
  int rbase_loc = (w & 1) * 16 + ((lane >> 4) << 2);
  #pragma unroll
  for (int t = 0; t < 2; ++t) {
    int col = (ntbase + t) * 16 + cbase;
    #pragma unroll
    for (int rg = 0; rg < 4; ++rg) {
      int grow = n0 + rbase_loc + rg;
      if (grow < M) h_pre[(size_t)grow * 64 + col] = f2bf(acc[t][rg]);
    }
  }
  // stats epilogue (reuse LDS)
  __syncthreads();
  float* sp = (float*)&tile[0][0];        // [8][64]
  float* sq = sp + 8 * 64;
  int strip = (w & 1) * 4 + (lane >> 4);
  #pragma unroll
  for (int t = 0; t < 2; ++t) {
    float cs = 0.f, cq = 0.f;
    #pragma unroll
    for (int rg = 0; rg < 4; ++rg) {
      int grow = n0 + rbase_loc + rg;
      float v = (grow < M) ? acc[t][rg] : 0.f;
      cs += v; cq += v * v;
    }
    int col = (ntbase + t) * 16 + cbase;
    sp[strip * 64 + col] = cs;
    sq[strip * 64 + col] = cq;
  }
  __syncthreads();
  if (tid < 64) {
    float s = 0.f, q = 0.f;
    #pragma unroll
    for (int g = 0; g < 8; g++) { s += sp[g * 64 + tid]; q += sq[g * 64 + tid]; }
    part[(size_t)blockIdx.x * 128 + tid] = s;
    part[(size_t)blockIdx.x * 128 + 64 + tid] = q;
  }
}

// gemm2 with fused bn+relu on A (h_pre) using ss1 -> z bf16, s2 bf16.
__global__ __launch_bounds__(256) void k_gemm2bn(
    const unsigned short* __restrict__ hp, int M,
    const unsigned short* __restrict__ Wb, int nslab,
    const float* __restrict__ ss,
    unsigned short* __restrict__ outLinB, unsigned short* __restrict__ outSelf) {
  __shared__ float sss[128];
  if (threadIdx.x < 128) sss[threadIdx.x] = ss[threadIdx.x];
  __syncthreads();
  int m0 = blockIdx.x * 64;
  int wid = threadIdx.x >> 6;
  int lane = threadIdx.x & 63;
  int mrow = m0 + wid * 16 + (lane & 15);
  int mload = (mrow < M) ? mrow : (M - 1);
  int cb = 8 * (lane >> 4);
  const unsigned short* arow = hp + (size_t)mload * 64 + cb;
  ushort4 u0 = *(const ushort4*)(arow);
  ushort4 u1 = *(const ushort4*)(arow + 4);
  ushort4 u2 = *(const ushort4*)(arow + 32);
  ushort4 u3 = *(const ushort4*)(arow + 36);
  bf16x8 a0, a1;
  #pragma unroll
  for (int j = 0; j < 4; j++) {
    unsigned short uu0 = (&u0.x)[j], uu1 = (&u1.x)[j], uu2 = (&u2.x)[j], uu3 = (&u3.x)[j];
    a0[j]     = (short)f2bf(fmaxf(fmaf(bf2f(uu0), sss[cb + j],      sss[64 + cb + j]), 0.f));
    a0[j + 4] = (short)f2bf(fmaxf(fmaf(bf2f(uu1), sss[cb + 4 + j],  sss[64 + cb + 4 + j]), 0.f));
    a1[j]     = (short)f2bf(fmaxf(fmaf(bf2f(uu2), sss[cb + 32 + j], sss[64 + cb + 32 + j]), 0.f));
    a1[j + 4] = (short)f2bf(fmaxf(fmaf(bf2f(uu3), sss[cb + 36 + j], sss[64 + cb + 36 + j]), 0.f));
  }
  int rbase = m0 + wid * 16 + ((lane >> 4) << 2);
  int cbase = lane & 15;
  for (int slab = 0; slab <= nslab; ++slab) {
    const unsigned short* wrow = Wb + ((size_t)slab * 64 + (lane & 15)) * 64 + 8 * (lane >> 4);
    unsigned short* op = (slab < nslab) ? (outLinB + (size_t)slab * M * 64) : outSelf;
    #pragma unroll
    for (int nt = 0; nt < 4; ++nt) {
      bf16x8 b0 = *(const bf16x8*)(wrow + nt * 16 * 64);
      bf16x8 b1 = *(const bf16x8*)(wrow + nt * 16 * 64 + 32);
      f32x4 c = {};
      c = __builtin_amdgcn_mfma_f32_16x16x32_bf16(a0, b0, c, 0, 0, 0);
      c = __builtin_amdgcn_mfma_f32_16x16x32_bf16(a1, b1, c, 0, 0, 0);
      int col = nt * 16 + cbase;
      #pragma unroll
      for (int rg = 0; rg < 4; ++rg) {
        int grow = rbase + rg;
        if (grow < M) op[(size_t)grow * 64 + col] = f2bf(c[rg]);
      }
    }
  }
}

// layer2 stats: s-major, descT single load, inline 1/d scaling.
__global__ __launch_bounds__(256) void k_gather2_stats(
    const unsigned* __restrict__ descT, const unsigned* __restrict__ ep4,
    const unsigned short* __restrict__ z, const unsigned short* __restrict__ s2,
    float* __restrict__ part, int N, int R) {
  int lane = threadIdx.x & 63;
  int wid = threadIdx.x >> 6;
  int l16 = lane & 15;
  int lg = lane >> 4;
  int c0 = l16 * 4;
  int grp = blockIdx.x * 16 + wid * 4 + lg;
  int ngrp = gridDim.x * 16;
  int NR = N * R;
  float lsum[4] = {0.f, 0.f, 0.f, 0.f}, lsq[4] = {0.f, 0.f, 0.f, 0.f};
  for (int s = grp; s < NR; s += ngrp) {
    unsigned r = (unsigned)s / (unsigned)N;
    int n = s - (int)r * N;
    unsigned desc = descT[s];
    int k = (int)(desc & 0xFFFFFu);
    int cnt = (int)(desc >> 20);
    int k1 = k + cnt;
    float a0 = 0.f, a1 = 0.f, a2 = 0.f, a3 = 0.f, d = 0.f;
    for (; k + 1 < k1; k += 2) {
      unsigned pA = ep4[k], pB = ep4[k + 1];
      ushort4 uA = *(const ushort4*)&z[(size_t)(pA & 0xFFFFu) * 64 + c0];
      ushort4 uB = *(const ushort4*)&z[(size_t)(pB & 0xFFFFu) * 64 + c0];
      float wA = bf2f((unsigned short)(pA >> 16));
      float wB = bf2f((unsigned short)(pB >> 16));
      d += wA + wB;
      a0 = fmaf(wA, bf2f(uA.x), a0); a1 = fmaf(wA, bf2f(uA.y), a1);
      a2 = fmaf(wA, bf2f(uA.z), a2); a3 = fmaf(wA, bf2f(uA.w), a3);
      a0 = fmaf(wB, bf2f(uB.x), a0); a1 = fmaf(wB, bf2f(uB.y), a1);
      a2 = fmaf(wB, bf2f(uB.z), a2); a3 = fmaf(wB, bf2f(uB.w), a3);
    }
    if (k < k1) {
      unsigned p = ep4[k];
      float w = bf2f((unsigned short)(p >> 16));
      ushort4 u = *(const ushort4*)&z[(size_t)(p & 0xFFFFu) * 64 + c0];
      d += w;
      a0 = fmaf(w, bf2f(u.x), a0); a1 = fmaf(w, bf2f(u.y), a1);
      a2 = fmaf(w, bf2f(u.z), a2); a3 = fmaf(w, bf2f(u.w), a3);
    }
    if (d != 0.f) {
      float inv = 1.f / d;
      a0 *= inv; a1 *= inv; a2 *= inv; a3 *= inv;
    }
    ushort4 su = *(const ushort4*)&s2[(size_t)n * 64 + c0];
    float v0 = a0 + bf2f(su.x), v1 = a1 + bf2f(su.y);
    float v2 = a2 + bf2f(su.z), v3 = a3 + bf2f(su.w);
    lsum[0] += v0; lsq[0] += v0 * v0;
    lsum[1] += v1; lsq[1] += v1 * v1;
    lsum[2] += v2; lsq[2] += v2 * v2;
    lsum[3] += v3; lsq[3] += v3 * v3;
  }
  __shared__ float sp[16][64], sq[16][64];
  int g = wid * 4 + lg;
  #pragma unroll
  for (int i = 0; i < 4; i++) { sp[g][c0 + i] = lsum[i]; sq[g][c0 + i] = lsq[i]; }
  __syncthreads();
  if (threadIdx.x < 64) {
    int j = threadIdx.x;
    float s = 0.f, q = 0.f;
    #pragma unroll
    for (int gg = 0; gg < 16; gg++) { s += sp[gg][j]; q += sq[gg][j]; }
    part[(size_t)blockIdx.x * 128 + j] = s;
    part[(size_t)blockIdx.x * 128 + 64 + j] = q;
  }
}

// layer2 write: s-major, descT, inline 1/d, BN+relu, contiguous f32 to d_out.
__global__ __launch_bounds__(256) void k_gather2_write(
    const unsigned* __restrict__ descT, const unsigned* __restrict__ ep4,
    const unsigned short* __restrict__ z, const unsigned short* __restrict__ s2,
    const float* __restrict__ ss, float* __restrict__ out, int N, int R) {
  int lane = threadIdx.x & 63;
  int wid = threadIdx.x >> 6;
  int l16 = lane & 15;
  int lg = lane >> 4;
  int c0 = l16 * 4;
  float sc0 = ss[c0], sc1 = ss[c0 + 1], sc2 = ss[c0 + 2], sc3 = ss[c0 + 3];
  float sh0 = ss[64 + c0], sh1 = ss[64 + c0 + 1], sh2 = ss[64 + c0 + 2], sh3 = ss[64 + c0 + 3];
  int grp = blockIdx.x * 16 + wid * 4 + lg;
  int ngrp = gridDim.x * 16;
  int NR = N * R;
  for (int s = grp; s < NR; s += ngrp) {
    unsigned r = (unsigned)s / (unsigned)N;
    int n = s - (int)r * N;
    unsigned desc = descT[s];
    int k = (int)(desc & 0xFFFFFu);
    int cnt = (int)(desc >> 20);
    int k1 = k + cnt;
    float a0 = 0.f, a1 = 0.f, a2 = 0.f, a3 = 0.f, d = 0.f;
    for (; k + 1 < k1; k += 2) {
      unsigned pA = ep4[k], pB = ep4[k + 1];
      ushort4 uA = *(const ushort4*)&z[(size_t)(pA & 0xFFFFu) * 64 + c0];
      ushort4 uB = *(const ushort4*)&z[(size_t)(pB & 0xFFFFu) * 64 + c0];
      float wA = bf2f((unsigned short)(pA >> 16));
      float wB = bf2f((unsigned short)(pB >> 16));
      d += wA + wB;
      a0 = fmaf(wA, bf2f(uA.x), a0); a1 = fmaf(wA, bf2f(uA.y), a1);
      a2 = fmaf(wA, bf2f(uA.z), a2); a3 = fmaf(wA, bf2f(uA.w), a3);
      a0 = fmaf(wB, bf2f(uB.x), a0); a1 = fmaf(wB, bf2f(uB.y), a1);
      a2 = fmaf(wB, bf2f(uB.z), a2); a3 = fmaf(wB, bf2f(uB.w), a3);
    }
    if (k < k1) {
      unsigned p = ep4[k];
      float w = bf2f((unsigned short)(p >> 16));
      ushort4 u = *(const ushort4*)&z[(size_t)(p & 0xFFFFu) * 64 + c0];
      d += w;
      a0 = fmaf(w, bf2f(u.x), a0); a1 = fmaf(w, bf2f(u.y), a1);
      a2 = fmaf(w, bf2f(u.z), a2); a3 = fmaf(w, bf2f(u.w), a3);
    }
    if (d != 0.f) {
      float inv = 1.f / d;
      a0 *= inv; a1 *= inv; a2 *= inv; a3 *= inv;
    }
    ushort4 su = *(const ushort4*)&s2[(size_t)n * 64 + c0];
    float v0 = fmaxf(fmaf(a0 + bf2f(su.x), sc0, sh0), 0.f);
    float v1 = fmaxf(fmaf(a1 + bf2f(su.y), sc1, sh1), 0.f);
    float v2 = fmaxf(fmaf(a2 + bf2f(su.z), sc2, sh2), 0.f);
    float v3 = fmaxf(fmaf(a3 + bf2f(su.w), sc3, sh3), 0.f);
    *(float4*)&out[(size_t)s * 64 + c0] = make_float4(v0, v1, v2, v3);
  }
}

// stage-1 reduce: part[P][128] -> part2[RED_BLOCKS][128]
__global__ __launch_bounds__(256) void k_red1(const float* __restrict__ part,
                                              float* __restrict__ part2, int P) {
  int j = threadIdx.x & 127;
  int g = threadIdx.x >> 7;
  int rows = (P + RED_BLOCKS - 1) / RED_BLOCKS;
  int base = blockIdx.x * rows;
  float acc = 0.f;
  for (int i = g; i < rows; i += 2) {
    int idx = base + i;
    if (idx < P) acc += part[(size_t)idx * 128 + j];
  }
  __shared__ float red[2][128];
  red[g][j] = acc;
  __syncthreads();
  if (threadIdx.x < 128) part2[(size_t)blockIdx.x * 128 + j] = red[0][j] + red[1][j];
}

__global__ __launch_bounds__(1024) void k_bnstats(
    const float* __restrict__ part, int P, float M,
    const float* __restrict__ gamma, const float* __restrict__ beta,
    float* __restrict__ ss) {
  __shared__ float red[1024];
  int tid = threadIdx.x;
  int j = tid & 127;
  int g = tid >> 7;
  float acc = 0.f;
  for (int i = g; i < P; i += 8) acc += part[(size_t)i * 128 + j];
  red[tid] = acc;
  __syncthreads();
  if (tid < 128) {
    float s = 0.f;
    for (int gg = 0; gg < 8; gg++) s += red[gg * 128 + tid];
    red[tid] = s;
  }
  __syncthreads();
  if (tid < 64) {
    float s = red[tid], q = red[64 + tid];
    float mean = s / M;
    float var = q / M - mean * mean;
    float sc = gamma[tid] / sqrtf(var + 1e-5f);
    ss[tid] = sc;
    ss[64 + tid] = beta[tid] - mean * sc;
  }
}

extern "C" void kernel_launch(void* const* d_in, const int* in_sizes, int n_in,
                              void* d_out, int out_size, void* d_ws, size_t ws_size,
                              hipStream_t stream) {
  const float* x        = (const float*)d_in[0];
  const float* edge_w   = (const float*)d_in[1];
  const float* W_lin1   = (const float*)d_in[2];
  const float* W_self1  = (const float*)d_in[4];
  const float* gamma1   = (const float*)d_in[6];
  const float* beta1    = (const float*)d_in[7];
  const float* W_lin2   = (const float*)d_in[8];
  const float* W_self2  = (const float*)d_in[10];
  const float* gamma2   = (const float*)d_in[12];
  const float* beta2    = (const float*)d_in[13];
  const int* node_in    = (const int*)d_in[14];
  const int* node_out   = (const int*)d_in[15];
  const int* relation   = (const int*)d_in[16];

  int N = in_sizes[0] / 64;           // 50000
  int E = in_sizes[1];                // 800000
  int R = in_sizes[2] / (64 * 64);    // 8
  int NR = N * R;
  int NB = (NR + SCAN_CHUNK - 1) / SCAN_CHUNK;

  char* p = (char*)d_ws;
  auto alloc = [&](size_t bytes) { char* r = p; p += (bytes + 255) & ~(size_t)255; return r; };
  int* cnt      = (int*)alloc(4ull * NR);
  int* rowptr   = (int*)alloc(4ull * (NR + 1));
  unsigned* descT = (unsigned*)alloc(4ull * NR);
  int* tmp      = (int*)alloc(4ull * E);
  int* bsum     = (int*)alloc(4ull * NB);
  int* bpre     = (int*)alloc(4ull * NB);
  unsigned* ep4 = (unsigned*)alloc(4ull * E);
  unsigned short* wb1 = (unsigned short*)alloc(2ull * 64 * (R * 64 + 64));
  unsigned short* wb2 = (unsigned short*)alloc(2ull * 2 * 64 * 64);
  unsigned short* xb    = (unsigned short*)alloc(2ull * N * 64);
  unsigned short* h_pre = (unsigned short*)alloc(2ull * N * 64);
  unsigned short* z     = (unsigned short*)alloc(2ull * N * 64);
  unsigned short* s2    = (unsigned short*)alloc(2ull * N * 64);
  float* part   = (float*)alloc(4ull * GATHER_GRID * 128);
  float* part2  = (float*)alloc(4ull * RED_BLOCKS * 128);
  float* ss1    = (float*)alloc(4ull * 128);
  float* ss2    = (float*)alloc(4ull * 128);

  int mblocks1 = (N + L1_NODES - 1) / L1_NODES;   // 1563
  int mblocks  = (N + 63) / 64;                   // 782

  k_zeropack<<<ZERO_BLOCKS + PACK_BLOCKS, 256, 0, stream>>>(
      cnt, NR, R, W_lin1, W_self1, W_lin2, W_self2, wb1, wb2);
  k_countx<<<XB_BLOCKS + COUNT_BLOCKS, 256, 0, stream>>>(
      node_out, relation, cnt, tmp, E, R, (const float4*)x, (ushort4*)xb, N * 64 / 4);
  k_scan1<<<NB, 256, 0, stream>>>(cnt, bsum, NR);
  k_scan2<<<1, 64, 0, stream>>>(bsum, bpre, &rowptr[NR], NB);
  k_scan3<<<NB, 256, 0, stream>>>(cnt, bpre, rowptr, descT, NR, R, N);
  k_place<<<PLACE_BLOCKS, 256, 0, stream>>>(
      edge_w, node_out, node_in, relation, rowptr, tmp, ep4, E, R);

  // layer 1 (fused gather+GEMM+stats)
  k_layer1<<<mblocks1, 256, 0, stream>>>(rowptr, ep4, xb, wb1, h_pre, part, N, R);
  k_red1<<<RED_BLOCKS, 256, 0, stream>>>(part, part2, mblocks1);
  k_bnstats<<<1, 1024, 0, stream>>>(part2, RED_BLOCKS, (float)N, gamma1, beta1, ss1);

  // layer 2
  k_gemm2bn<<<mblocks, 256, 0, stream>>>(h_pre, N, wb2, 1, ss1, z, s2);
  k_gather2_stats<<<GATHER_GRID, 256, 0, stream>>>(descT, ep4, z, s2, part, N, R);
  k_red1<<<RED_BLOCKS, 256, 0, stream>>>(part, part2, GATHER_GRID);
  k_bnstats<<<1, 1024, 0, stream>>>(part2, RED_BLOCKS, (float)N * R, gamma2, beta2, ss2);
  k_gather2_write<<<GATHER_GRID, 256, 0, stream>>>(descT, ep4, z, s2, ss2, (float*)d_out, N, R);
}

// Round 12
// 285.261 us; speedup vs baseline: 1.0006x; 1.0006x over previous
//
#include <hip/hip_runtime.h>

// relationalGraphStack — round 10
// vs R9: k_gatherx+k_gemm1b+k_stats1 fused into k_layer1 (gather -> LDS tile ->
// MFMA K=576 -> h_pre, stats in epilogue): updx never touches HBM (saves 102MB
// round trip). k_norm killed: d accumulated alongside the weighted sums in the
// same unrolled loop (no serial pre-pass), result scaled by 1/d per segment.
// descT[s]=start|cnt<<20 gives g2 kernels one coalesced load per segment.

#define GATHER_GRID 2048
#define SCAN_CHUNK 4096
#define RED_BLOCKS 64
#define ZERO_BLOCKS 256
#define PACK_BLOCKS 16
#define XB_BLOCKS 64
#define COUNT_BLOCKS 2048
#define PLACE_BLOCKS 1024
#define L1_NODES 32

typedef short bf16x8 __attribute__((ext_vector_type(8)));
typedef float f32x4 __attribute__((ext_vector_type(4)));

static __device__ __forceinline__ float bf2f(unsigned short u) {
  return __uint_as_float(((unsigned)u) << 16);
}
static __device__ __forceinline__ unsigned short f2bf(float f) {
  unsigned u = __float_as_uint(f);
  u += 0x7FFFu + ((u >> 16) & 1u);  // round to nearest even
  return (unsigned short)(u >> 16);
}

// zero cnt + pack weights. wb1[j*576+k]: k<512 -> W_lin1[j*512+k], else W_self1.
// wb2[(s*64+j)*64+d]: s=0 W_lin2, s=1 W_self2.
__global__ void k_zeropack(int* __restrict__ cnt, int NR, int R,
                           const float* __restrict__ Wlin1, const float* __restrict__ Wself1,
                           const float* __restrict__ Wlin2, const float* __restrict__ Wself2,
                           unsigned short* __restrict__ wb1, unsigned short* __restrict__ wb2) {
  if (blockIdx.x < ZERO_BLOCKS) {
    int i = blockIdx.x * 256 + threadIdx.x;
    int stride = ZERO_BLOCKS * 256;
    for (int k = i; k < NR; k += stride) cnt[k] = 0;
  } else {
    int i = (blockIdx.x - ZERO_BLOCKS) * 256 + threadIdx.x;
    int stride = PACK_BLOCKS * 256;
    int KW = R * 64 + 64;                 // 576
    int n1 = 64 * KW;
    int n2 = 2 * 64 * 64;
    for (int t = i; t < n1 + n2; t += stride) {
      if (t < n1) {
        int j = t / KW, k = t - j * KW;
        float v = (k < R * 64) ? Wlin1[j * (R * 64) + k] : Wself1[j * 64 + (k - R * 64)];
        wb1[t] = f2bf(v);
      } else {
        int t2 = t - n1;
        int r = t2 >> 6, d = t2 & 63;
        float v = (r < 64) ? Wlin2[r * 64 + d] : Wself2[(r - 64) * 64 + d];
        wb2[t2] = f2bf(v);
      }
    }
  }
}

// blocks [0,XB_BLOCKS): x f32 -> xb bf16. blocks [XB_BLOCKS,...): count + rank tmp.
__global__ void k_countx(const int* __restrict__ node_out, const int* __restrict__ rel,
                         int* __restrict__ cnt, int* __restrict__ tmp, int E, int R,
                         const float4* __restrict__ xin, ushort4* __restrict__ xb, int n4) {
  if (blockIdx.x < XB_BLOCKS) {
    int i = blockIdx.x * 256 + threadIdx.x;
    int stride = XB_BLOCKS * 256;
    for (int k = i; k < n4; k += stride) {
      float4 v = xin[k];
      ushort4 o;
      o.x = f2bf(v.x); o.y = f2bf(v.y); o.z = f2bf(v.z); o.w = f2bf(v.w);
      xb[k] = o;
    }
  } else {
    int i = (blockIdx.x - XB_BLOCKS) * 256 + threadIdx.x;
    int stride = COUNT_BLOCKS * 256;
    for (int e = i; e < E; e += stride) {
      int seg = node_out[e] * R + rel[e];
      tmp[e] = atomicAdd(&cnt[seg], 1);
    }
  }
}

__global__ __launch_bounds__(256) void k_scan1(const int* __restrict__ cnt,
                                               int* __restrict__ bsum, int NR) {
  __shared__ int red[256];
  int tid = threadIdx.x;
  int base = blockIdx.x * SCAN_CHUNK;
  int s = 0;
  for (int i = tid; i < SCAN_CHUNK; i += 256) {
    int idx = base + i;
    if (idx < NR) s += cnt[idx];
  }
  red[tid] = s;
  __syncthreads();
  for (int off = 128; off > 0; off >>= 1) {
    if (tid < off) red[tid] += red[tid + off];
    __syncthreads();
  }
  if (tid == 0) bsum[blockIdx.x] = red[0];
}

__global__ void k_scan2(const int* __restrict__ bsum, int* __restrict__ bpre,
                        int* __restrict__ rowptr_end, int NB) {
  int lane = threadIdx.x;
  int carry = 0;
  for (int base = 0; base < NB; base += 64) {
    int i = base + lane;
    int v = (i < NB) ? bsum[i] : 0;
    int incl = v;
    #pragma unroll
    for (int off = 1; off < 64; off <<= 1) {
      int u = __shfl_up(incl, off);
      if (lane >= off) incl += u;
    }
    if (i < NB) bpre[i] = carry + incl - v;
    carry += __shfl(incl, 63);
  }
  if (lane == 0) *rowptr_end = carry;
}

// rowptr (n-major) + descT (s-major: descT[r*N+n] = start | cnt<<20)
__global__ __launch_bounds__(256) void k_scan3(const int* __restrict__ cnt,
                                               const int* __restrict__ bpre,
                                               int* __restrict__ rowptr,
                                               unsigned* __restrict__ descT,
                                               int NR, int R, int Nn) {
  __shared__ int wtot[4];
  int tid = threadIdx.x, lane = tid & 63, wid = tid >> 6;
  int base = blockIdx.x * SCAN_CHUNK + tid * 16;
  int v[16];
  int t = 0;
  #pragma unroll
  for (int i = 0; i < 16; i++) {
    int idx = base + i;
    v[i] = (idx < NR) ? cnt[idx] : 0;
    t += v[i];
  }
  int incl = t;
  #pragma unroll
  for (int off = 1; off < 64; off <<= 1) {
    int u = __shfl_up(incl, off);
    if (lane >= off) incl += u;
  }
  if (lane == 63) wtot[wid] = incl;
  __syncthreads();
  int woff = 0;
  for (int w = 0; w < wid; w++) woff += wtot[w];
  int start = bpre[blockIdx.x] + woff + incl - t;
  #pragma unroll
  for (int i = 0; i < 16; i++) {
    int idx = base + i;
    if (idx < NR) {
      rowptr[idx] = start;
      int n = (int)((unsigned)idx / (unsigned)R);
      int r = idx - n * R;
      descT[(size_t)r * Nn + n] = (unsigned)start | ((unsigned)v[i] << 20);
    }
    start += v[i];
  }
}

// placement, no atomics, 4B payload: ep4[rowptr[seg]+tmp[e]] = src | bf16(raw w)<<16
__global__ void k_place(const float* __restrict__ w, const int* __restrict__ node_out,
                        const int* __restrict__ node_in, const int* __restrict__ rel,
                        const int* __restrict__ rowptr, const int* __restrict__ tmp,
                        unsigned* __restrict__ ep4, int E, int R) {
  int i = blockIdx.x * blockDim.x + threadIdx.x;
  int stride = gridDim.x * blockDim.x;
  for (int e = i; e < E; e += stride) {
    int seg = node_out[e] * R + rel[e];
    int pos = rowptr[seg] + tmp[e];
    ep4[pos] = (unsigned)node_in[e] | ((unsigned)f2bf(w[e]) << 16);
  }
}

// Layer 1 fused: gather x per (node,r) -> LDS tile [32][512(+pad)], then
// MFMA K=576 (512 LDS + 64 xb) -> h_pre bf16; column stats in epilogue.
__global__ __launch_bounds__(256) void k_layer1(
    const int* __restrict__ rowptr, const unsigned* __restrict__ ep4,
    const unsigned short* __restrict__ xb, const unsigned short* __restrict__ wb1,
    unsigned short* __restrict__ h_pre, float* __restrict__ part, int M, int R) {
  __shared__ unsigned short tile[L1_NODES][520];   // 33,280 B
  int tid = threadIdx.x;
  int n0 = blockIdx.x * L1_NODES;
  {
    int gid = tid >> 4;      // 16 gather groups
    int l16 = tid & 15;
    int c0 = l16 * 4;
    int nseg = L1_NODES * R;
    for (int sl = gid; sl < nseg; sl += 16) {
      int nl = (int)((unsigned)sl / (unsigned)R);
      int r = sl - nl * R;
      int n = n0 + nl;
      float a0 = 0.f, a1 = 0.f, a2 = 0.f, a3 = 0.f, d = 0.f;
      if (n < M) {
        int seg = n * R + r;
        int k = rowptr[seg], k1 = rowptr[seg + 1];
        for (; k + 1 < k1; k += 2) {
          unsigned pA = ep4[k], pB = ep4[k + 1];
          ushort4 uA = *(const ushort4*)&xb[(size_t)(pA & 0xFFFFu) * 64 + c0];
          ushort4 uB = *(const ushort4*)&xb[(size_t)(pB & 0xFFFFu) * 64 + c0];
          float wA = bf2f((unsigned short)(pA >> 16));
          float wB = bf2f((unsigned short)(pB >> 16));
          d += wA + wB;
          a0 = fmaf(wA, bf2f(uA.x), a0); a1 = fmaf(wA, bf2f(uA.y), a1);
          a2 = fmaf(wA, bf2f(uA.z), a2); a3 = fmaf(wA, bf2f(uA.w), a3);
          a0 = fmaf(wB, bf2f(uB.x), a0); a1 = fmaf(wB, bf2f(uB.y), a1);
          a2 = fmaf(wB, bf2f(uB.z), a2); a3 = fmaf(wB, bf2f(uB.w), a3);
        }
        if (k < k1) {
          unsigned p = ep4[k];
          float w = bf2f((unsigned short)(p >> 16));
          ushort4 u = *(const ushort4*)&xb[(size_t)(p & 0xFFFFu) * 64 + c0];
          d += w;
          a0 = fmaf(w, bf2f(u.x), a0); a1 = fmaf(w, bf2f(u.y), a1);
          a2 = fmaf(w, bf2f(u.z), a2); a3 = fmaf(w, bf2f(u.w), a3);
        }
        if (d != 0.f) {
          float inv = 1.f / d;
          a0 *= inv; a1 *= inv; a2 *= inv; a3 *= inv;
        }
      }
      ushort4 o; o.x = f2bf(a0); o.y = f2bf(a1); o.z = f2bf(a2); o.w = f2bf(a3);
      *(ushort4*)&tile[nl][r * 64 + c0] = o;
    }
  }
  __syncthreads();
  // MFMA: 4 waves; wave w: rows (w&1)*16+[0,16), col-blocks nt = (w>>1)*2 + {0,1}
  int w = tid >> 6, lane = tid & 63;
  int rloc = (w & 1) * 16 + (lane & 15);
  int koff = 8 * (lane >> 4);
  const unsigned short* arow = &tile[rloc][koff];
  int gxrow = n0 + rloc; if (gxrow >= M) gxrow = M - 1;
  const unsigned short* aX = xb + (size_t)gxrow * 64 + koff;
  int ntbase = (w >> 1) * 2;
  const unsigned short* wr = wb1 + (size_t)(lane & 15) * 576 + koff;
  f32x4 acc[2] = {{0, 0, 0, 0}, {0, 0, 0, 0}};
  #pragma unroll
  for (int kk = 0; kk < 16; ++kk) {
    bf16x8 a = *(const bf16x8*)(arow + kk * 32);
    #pragma unroll
    for (int t = 0; t < 2; ++t) {
      bf16x8 b = *(const bf16x8*)(wr + (size_t)(ntbase + t) * 16 * 576 + kk * 32);
      acc[t] = __builtin_amdgcn_mfma_f32_16x16x32_bf16(a, b, acc[t], 0, 0, 0);
    }
  }
  #pragma unroll
  for (int kk = 0; kk < 2; ++kk) {
    bf16x8 a = *(const bf16x8*)(aX + kk * 32);
    #pragma unroll
    for (int t = 0; t < 2; ++t) {
      bf16x8 b = *(const bf16x8*)(wr + (size_t)(ntbase + t) * 16 * 576 + 512 + kk * 32);
      acc[t] = __builtin_amdgcn_mfma_f32_16x16x32_bf16(a, b, acc[t], 0, 0, 0);
    }
  }
  int cbase = lane & 15;
  int rbase_loc = (w & 1) * 16 + ((lane >> 4) << 2);
  #pragma unroll
  for (int t = 0; t < 2; ++t) {
    int col = (ntbase + t) * 16 + cbase;
    #pragma unroll
    for (int rg = 0; rg < 4; ++rg) {
      int grow = n0 + rbase_loc + rg;
      if (grow < M) h_pre[(size_t)grow * 64 + col] = f2bf(acc[t][rg]);
    }
  }
  // stats epilogue (reuse LDS)
  __syncthreads();
  float* sp = (float*)&tile[0][0];        // [8][64]
  float* sq = sp + 8 * 64;
  int strip = (w & 1) * 4 + (lane >> 4);
  #pragma unroll
  for (int t = 0; t < 2; ++t) {
    float cs = 0.f, cq = 0.f;
    #pragma unroll
    for (int rg = 0; rg < 4; ++rg) {
      int grow = n0 + rbase_loc + rg;
      float v = (grow < M) ? acc[t][rg] : 0.f;
      cs += v; cq += v * v;
    }
    int col = (ntbase + t) * 16 + cbase;
    sp[strip * 64 + col] = cs;
    sq[strip * 64 + col] = cq;
  }
  __syncthreads();
  if (tid < 64) {
    float s = 0.f, q = 0.f;
    #pragma unroll
    for (int g = 0; g < 8; g++) { s += sp[g * 64 + tid]; q += sq[g * 64 + tid]; }
    part[(size_t)blockIdx.x * 128 + tid] = s;
    part[(size_t)blockIdx.x * 128 + 64 + tid] = q;
  }
}

// gemm2 with fused bn+relu on A (h_pre) using ss1 -> z bf16, s2 bf16.
__global__ __launch_bounds__(256) void k_gemm2bn(
    const unsigned short* __restrict__ hp, int M,
    const unsigned short* __restrict__ Wb, int nslab,
    const float* __restrict__ ss,
    unsigned short* __restrict__ outLinB, unsigned short* __restrict__ outSelf) {
  __shared__ float sss[128];
  if (threadIdx.x < 128) sss[threadIdx.x] = ss[threadIdx.x];
  __syncthreads();
  int m0 = blockIdx.x * 64;
  int wid = threadIdx.x >> 6;
  int lane = threadIdx.x & 63;
  int mrow = m0 + wid * 16 + (lane & 15);
  int mload = (mrow < M) ? mrow : (M - 1);
  int cb = 8 * (lane >> 4);
  const unsigned short* arow = hp + (size_t)mload * 64 + cb;
  ushort4 u0 = *(const ushort4*)(arow);
  ushort4 u1 = *(const ushort4*)(arow + 4);
  ushort4 u2 = *(const ushort4*)(arow + 32);
  ushort4 u3 = *(const ushort4*)(arow + 36);
  bf16x8 a0, a1;
  #pragma unroll
  for (int j = 0; j < 4; j++) {
    unsigned short uu0 = (&u0.x)[j], uu1 = (&u1.x)[j], uu2 = (&u2.x)[j], uu3 = (&u3.x)[j];
    a0[j]     = (short)f2bf(fmaxf(fmaf(bf2f(uu0), sss[cb + j],      sss[64 + cb + j]), 0.f));
    a0[j + 4] = (short)f2bf(fmaxf(fmaf(bf2f(uu1), sss[cb + 4 + j],  sss[64 + cb + 4 + j]), 0.f));
    a1[j]     = (short)f2bf(fmaxf(fmaf(bf2f(uu2), sss[cb + 32 + j], sss[64 + cb + 32 + j]), 0.f));
    a1[j + 4] = (short)f2bf(fmaxf(fmaf(bf2f(uu3), sss[cb + 36 + j], sss[64 + cb + 36 + j]), 0.f));
  }
  int rbase = m0 + wid * 16 + ((lane >> 4) << 2);
  int cbase = lane & 15;
  for (int slab = 0; slab <= nslab; ++slab) {
    const unsigned short* wrow = Wb + ((size_t)slab * 64 + (lane & 15)) * 64 + 8 * (lane >> 4);
    unsigned short* op = (slab < nslab) ? (outLinB + (size_t)slab * M * 64) : outSelf;
    #pragma unroll
    for (int nt = 0; nt < 4; ++nt) {
      bf16x8 b0 = *(const bf16x8*)(wrow + nt * 16 * 64);
      bf16x8 b1 = *(const bf16x8*)(wrow + nt * 16 * 64 + 32);
      f32x4 c = {};
      c = __builtin_amdgcn_mfma_f32_16x16x32_bf16(a0, b0, c, 0, 0, 0);
      c = __builtin_amdgcn_mfma_f32_16x16x32_bf16(a1, b1, c, 0, 0, 0);
      int col = nt * 16 + cbase;
      #pragma unroll
      for (int rg = 0; rg < 4; ++rg) {
        int grow = rbase + rg;
        if (grow < M) op[(size_t)grow * 64 + col] = f2bf(c[rg]);
      }
    }
  }
}

// layer2 stats: s-major, descT single load, inline 1/d scaling.
__global__ __launch_bounds__(256) void k_gather2_stats(
    const unsigned* __restrict__ descT, const unsigned* __restrict__ ep4,
    const unsigned short* __restrict__ z, const unsigned short* __restrict__ s2,
    float* __restrict__ part, int N, int R) {
  int lane = threadIdx.x & 63;
  int wid = threadIdx.x >> 6;
  int l16 = lane & 15;
  int lg = lane >> 4;
  int c0 = l16 * 4;
  int grp = blockIdx.x * 16 + wid * 4 + lg;
  int ngrp = gridDim.x * 16;
  int NR = N * R;
  float lsum[4] = {0.f, 0.f, 0.f, 0.f}, lsq[4] = {0.f, 0.f, 0.f, 0.f};
  for (int s = grp; s < NR; s += ngrp) {
    unsigned r = (unsigned)s / (unsigned)N;
    int n = s - (int)r * N;
    unsigned desc = descT[s];
    int k = (int)(desc & 0xFFFFFu);
    int cnt = (int)(desc >> 20);
    int k1 = k + cnt;
    float a0 = 0.f, a1 = 0.f, a2 = 0.f, a3 = 0.f, d = 0.f;
    for (; k + 1 < k1; k += 2) {
      unsigned pA = ep4[k], pB = ep4[k + 1];
      ushort4 uA = *(const ushort4*)&z[(size_t)(pA & 0xFFFFu) * 64 + c0];
      ushort4 uB = *(const ushort4*)&z[(size_t)(pB & 0xFFFFu) * 64 + c0];
      float wA = bf2f((unsigned short)(pA >> 16));
      float wB = bf2f((unsigned short)(pB >> 16));
      d += wA + wB;
      a0 = fmaf(wA, bf2f(uA.x), a0); a1 = fmaf(wA, bf2f(uA.y), a1);
      a2 = fmaf(wA, bf2f(uA.z), a2); a3 = fmaf(wA, bf2f(uA.w), a3);
      a0 = fmaf(wB, bf2f(uB.x), a0); a1 = fmaf(wB, bf2f(uB.y), a1);
      a2 = fmaf(wB, bf2f(uB.z), a2); a3 = fmaf(wB, bf2f(uB.w), a3);
    }
    if (k < k1) {
      unsigned p = ep4[k];
      float w = bf2f((unsigned short)(p >> 16));
      ushort4 u = *(const ushort4*)&z[(size_t)(p & 0xFFFFu) * 64 + c0];
      d += w;
      a0 = fmaf(w, bf2f(u.x), a0); a1 = fmaf(w, bf2f(u.y), a1);
      a2 = fmaf(w, bf2f(u.z), a2); a3 = fmaf(w, bf2f(u.w), a3);
    }
    if (d != 0.f) {
      float inv = 1.f / d;
      a0 *= inv; a1 *= inv; a2 *= inv; a3 *= inv;
    }
    ushort4 su = *(const ushort4*)&s2[(size_t)n * 64 + c0];
    float v0 = a0 + bf2f(su.x), v1 = a1 + bf2f(su.y);
    float v2 = a2 + bf2f(su.z), v3 = a3 + bf2f(su.w);
    lsum[0] += v0; lsq[0] += v0 * v0;
    lsum[1] += v1; lsq[1] += v1 * v1;
    lsum[2] += v2; lsq[2] += v2 * v2;
    lsum[3] += v3; lsq[3] += v3 * v3;
  }
  __shared__ float sp[16][64], sq[16][64];
  int g = wid * 4 + lg;
  #pragma unroll
  for (int i = 0; i < 4; i++) { sp[g][c0 + i] = lsum[i]; sq[g][c0 + i] = lsq[i]; }
  __syncthreads();
  if (threadIdx.x < 64) {
    int j = threadIdx.x;
    float s = 0.f, q = 0.f;
    #pragma unroll
    for (int gg = 0; gg < 16; gg++) { s += sp[gg][j]; q += sq[gg][j]; }
    part[(size_t)blockIdx.x * 128 + j] = s;
    part[(size_t)blockIdx.x * 128 + 64 + j] = q;
  }
}

// layer2 write: s-major, descT, inline 1/d, BN+relu, contiguous f32 to d_out.
__global__ __launch_bounds__(256) void k_gather2_write(
    const unsigned* __restrict__ descT, const unsigned* __restrict__ ep4,
    const unsigned short* __restrict__ z, const unsigned short* __restrict__ s2,
    const float* __restrict__ ss, float* __restrict__ out, int N, int R) {
  int lane = threadIdx.x & 63;
  int wid = threadIdx.x >> 6;
  int l16 = lane & 15;
  int lg = lane >> 4;
  int c0 = l16 * 4;
  float sc0 = ss[c0], sc1 = ss[c0 + 1], sc2 = ss[c0 + 2], sc3 = ss[c0 + 3];
  float sh0 = ss[64 + c0], sh1 = ss[64 + c0 + 1], sh2 = ss[64 + c0 + 2], sh3 = ss[64 + c0 + 3];
  int grp = blockIdx.x * 16 + wid * 4 + lg;
  int ngrp = gridDim.x * 16;
  int NR = N * R;
  for (int s = grp; s < NR; s += ngrp) {
    unsigned r = (unsigned)s / (unsigned)N;
    int n = s - (int)r * N;
    unsigned desc = descT[s];
    int k = (int)(desc & 0xFFFFFu);
    int cnt = (int)(desc >> 20);
    int k1 = k + cnt;
    float a0 = 0.f, a1 = 0.f, a2 = 0.f, a3 = 0.f, d = 0.f;
    for (; k + 1 < k1; k += 2) {
      unsigned pA = ep4[k], pB = ep4[k + 1];
      ushort4 uA = *(const ushort4*)&z[(size_t)(pA & 0xFFFFu) * 64 + c0];
      ushort4 uB = *(const ushort4*)&z[(size_t)(pB & 0xFFFFu) * 64 + c0];
      float wA = bf2f((unsigned short)(pA >> 16));
      float wB = bf2f((unsigned short)(pB >> 16));
      d += wA + wB;
      a0 = fmaf(wA, bf2f(uA.x), a0); a1 = fmaf(wA, bf2f(uA.y), a1);
      a2 = fmaf(wA, bf2f(uA.z), a2); a3 = fmaf(wA, bf2f(uA.w), a3);
      a0 = fmaf(wB, bf2f(uB.x), a0); a1 = fmaf(wB, bf2f(uB.y), a1);
      a2 = fmaf(wB, bf2f(uB.z), a2); a3 = fmaf(wB, bf2f(uB.w), a3);
    }
    if (k < k1) {
      unsigned p = ep4[k];
      float w = bf2f((unsigned short)(p >> 16));
      ushort4 u = *(const ushort4*)&z[(size_t)(p & 0xFFFFu) * 64 + c0];
      d += w;
      a0 = fmaf(w, bf2f(u.x), a0); a1 = fmaf(w, bf2f(u.y), a1);
      a2 = fmaf(w, bf2f(u.z), a2); a3 = fmaf(w, bf2f(u.w), a3);
    }
    if (d != 0.f) {
      float inv = 1.f / d;
      a0 *= inv; a1 *= inv; a2 *= inv; a3 *= inv;
    }
    ushort4 su = *(const ushort4*)&s2[(size_t)n * 64 + c0];
    float v0 = fmaxf(fmaf(a0 + bf2f(su.x), sc0, sh0), 0.f);
    float v1 = fmaxf(fmaf(a1 + bf2f(su.y), sc1, sh1), 0.f);
    float v2 = fmaxf(fmaf(a2 + bf2f(su.z), sc2, sh2), 0.f);
    float v3 = fmaxf(fmaf(a3 + bf2f(su.w), sc3, sh3), 0.f);
    *(float4*)&out[(size_t)s * 64 + c0] = make_float4(v0, v1, v2, v3);
  }
}

// stage-1 reduce: part[P][128] -> part2[RED_BLOCKS][128]
__global__ __launch_bounds__(256) void k_red1(const float* __restrict__ part,
                                              float* __restrict__ part2, int P) {
  int j = threadIdx.x & 127;
  int g = threadIdx.x >> 7;
  int rows = (P + RED_BLOCKS - 1) / RED_BLOCKS;
  int base = blockIdx.x * rows;
  float acc = 0.f;
  for (int i = g; i < rows; i += 2) {
    int idx = base + i;
    if (idx < P) acc += part[(size_t)idx * 128 + j];
  }
  __shared__ float red[2][128];
  red[g][j] = acc;
  __syncthreads();
  if (threadIdx.x < 128) part2[(size_t)blockIdx.x * 128 + j] = red[0][j] + red[1][j];
}

__global__ __launch_bounds__(1024) void k_bnstats(
    const float* __restrict__ part, int P, float M,
    const float* __restrict__ gamma, const float* __restrict__ beta,
    float* __restrict__ ss) {
  __shared__ float red[1024];
  int tid = threadIdx.x;
  int j = tid & 127;
  int g = tid >> 7;
  float acc = 0.f;
  for (int i = g; i < P; i += 8) acc += part[(size_t)i * 128 + j];
  red[tid] = acc;
  __syncthreads();
  if (tid < 128) {
    float s = 0.f;
    for (int gg = 0; gg < 8; gg++) s += red[gg * 128 + tid];
    red[tid] = s;
  }
  __syncthreads();
  if (tid < 64) {
    float s = red[tid], q = red[64 + tid];
    float mean = s / M;
    float var = q / M - mean * mean;
    float sc = gamma[tid] / sqrtf(var + 1e-5f);
    ss[tid] = sc;
    ss[64 + tid] = beta[tid] - mean * sc;
  }
}

extern "C" void kernel_launch(void* const* d_in, const int* in_sizes, int n_in,
                              void* d_out, int out_size, void* d_ws, size_t ws_size,
                              hipStream_t stream) {
  const float* x        = (const float*)d_in[0];
  const float* edge_w   = (const float*)d_in[1];
  const float* W_lin1   = (const float*)d_in[2];
  const float* W_self1  = (const float*)d_in[4];
  const float* gamma1   = (const float*)d_in[6];
  const float* beta1    = (const float*)d_in[7];
  const float* W_lin2   = (const float*)d_in[8];
  const float* W_self2  = (const float*)d_in[10];
  const float* gamma2   = (const float*)d_in[12];
  const float* beta2    = (const float*)d_in[13];
  const int* node_in    = (const int*)d_in[14];
  const int* node_out   = (const int*)d_in[15];
  const int* relation   = (const int*)d_in[16];

  int N = in_sizes[0] / 64;           // 50000
  int E = in_sizes[1];                // 800000
  int R = in_sizes[2] / (64 * 64);    // 8
  int NR = N * R;
  int NB = (NR + SCAN_CHUNK - 1) / SCAN_CHUNK;

  char* p = (char*)d_ws;
  auto alloc = [&](size_t bytes) { char* r = p; p += (bytes + 255) & ~(size_t)255; return r; };
  int* cnt      = (int*)alloc(4ull * NR);
  int* rowptr   = (int*)alloc(4ull * (NR + 1));
  unsigned* descT = (unsigned*)alloc(4ull * NR);
  int* tmp      = (int*)alloc(4ull * E);
  int* bsum     = (int*)alloc(4ull * NB);
  int* bpre     = (int*)alloc(4ull * NB);
  unsigned* ep4 = (unsigned*)alloc(4ull * E);
  unsigned short* wb1 = (unsigned short*)alloc(2ull * 64 * (R * 64 + 64));
  unsigned short* wb2 = (unsigned short*)alloc(2ull * 2 * 64 * 64);
  unsigned short* xb    = (unsigned short*)alloc(2ull * N * 64);
  unsigned short* h_pre = (unsigned short*)alloc(2ull * N * 64);
  unsigned short* z     = (unsigned short*)alloc(2ull * N * 64);
  unsigned short* s2    = (unsigned short*)alloc(2ull * N * 64);
  float* part   = (float*)alloc(4ull * GATHER_GRID * 128);
  float* part2  = (float*)alloc(4ull * RED_BLOCKS * 128);
  float* ss1    = (float*)alloc(4ull * 128);
  float* ss2    = (float*)alloc(4ull * 128);

  int mblocks1 = (N + L1_NODES - 1) / L1_NODES;   // 1563
  int mblocks  = (N + 63) / 64;                   // 782

  k_zeropack<<<ZERO_BLOCKS + PACK_BLOCKS, 256, 0, stream>>>(
      cnt, NR, R, W_lin1, W_self1, W_lin2, W_self2, wb1, wb2);
  k_countx<<<XB_BLOCKS + COUNT_BLOCKS, 256, 0, stream>>>(
      node_out, relation, cnt, tmp, E, R, (const float4*)x, (ushort4*)xb, N * 64 / 4);
  k_scan1<<<NB, 256, 0, stream>>>(cnt, bsum, NR);
  k_scan2<<<1, 64, 0, stream>>>(bsum, bpre, &rowptr[NR], NB);
  k_scan3<<<NB, 256, 0, stream>>>(cnt, bpre, rowptr, descT, NR, R, N);
  k_place<<<PLACE_BLOCKS, 256, 0, stream>>>(
      edge_w, node_out, node_in, relation, rowptr, tmp, ep4, E, R);

  // layer 1 (fused gather+GEMM+stats)
  k_layer1<<<mblocks1, 256, 0, stream>>>(rowptr, ep4, xb, wb1, h_pre, part, N, R);
  k_red1<<<RED_BLOCKS, 256, 0, stream>>>(part, part2, mblocks1);
  k_bnstats<<<1, 1024, 0, stream>>>(part2, RED_BLOCKS, (float)N, gamma1, beta1, ss1);

  // layer 2
  k_gemm2bn<<<mblocks, 256, 0, stream>>>(h_pre, N, wb2, 1, ss1, z, s2);
  k_gather2_stats<<<GATHER_GRID, 256, 0, stream>>>(descT, ep4, z, s2, part, N, R);
  k_red1<<<RED_BLOCKS, 256, 0, stream>>>(part, part2, GATHER_GRID);
  k_bnstats<<<1, 1024, 0, stream>>>(part2, RED_BLOCKS, (float)N * R, gamma2, beta2, ss2);
  k_gather2_write<<<GATHER_GRID, 256, 0, stream>>>(descT, ep4, z, s2, ss2, (float*)d_out, N, R);
}

// Round 13
// 256.091 us; speedup vs baseline: 1.1145x; 1.1139x over previous
//
#include <hip/hip_runtime.h>

// relationalGraphStack — round 12 (recombination of proven-best pieces)
// R7 skeleton (GEMM1-first, gather y1) + R8's count∥gemm1 fusion (proven free)
// + R10's 4B ep, descT, single-pass inline-d normalization (k_norm gone).
// R10's LDS-fused layer1 reverted (96us: occupancy+straggler-tail).

#define GATHER_GRID 2048
#define SCAN_CHUNK 4096
#define RED_BLOCKS 64
#define ZERO_BLOCKS 256
#define PACK_BLOCKS 16
#define COUNT_BLOCKS 2048
#define PLACE_BLOCKS 1024

typedef short bf16x8 __attribute__((ext_vector_type(8)));
typedef float f32x4 __attribute__((ext_vector_type(4)));

static __device__ __forceinline__ float bf2f(unsigned short u) {
  return __uint_as_float(((unsigned)u) << 16);
}
static __device__ __forceinline__ unsigned short f2bf(float f) {
  unsigned u = __float_as_uint(f);
  u += 0x7FFFu + ((u >> 16) & 1u);  // round to nearest even
  return (unsigned short)(u >> 16);
}

// zero cnt + pack weights (R7 9-slab format for wb1; wb2 = [Wlin2; Wself2]).
__global__ void k_zeropack(int* __restrict__ cnt, int NR, int R,
                           const float* __restrict__ Wlin1, const float* __restrict__ Wself1,
                           const float* __restrict__ Wlin2, const float* __restrict__ Wself2,
                           unsigned short* __restrict__ wb1, unsigned short* __restrict__ wb2) {
  if (blockIdx.x < ZERO_BLOCKS) {
    int i = blockIdx.x * 256 + threadIdx.x;
    int stride = ZERO_BLOCKS * 256;
    for (int k = i; k < NR; k += stride) cnt[k] = 0;
  } else {
    int i = (blockIdx.x - ZERO_BLOCKS) * 256 + threadIdx.x;
    int stride = PACK_BLOCKS * 256;
    int n1 = (R + 1) * 64 * 64;
    int n2 = 2 * 64 * 64;
    for (int k = i; k < n1 + n2; k += stride) {
      if (k < n1) {
        int r = k >> 6, d = k & 63;
        float v;
        if (r < R * 64) {
          int s = r >> 6, j = r & 63;
          v = Wlin1[j * (R * 64) + s * 64 + d];
        } else {
          v = Wself1[(r - R * 64) * 64 + d];
        }
        wb1[k] = f2bf(v);
      } else {
        int k2 = k - n1;
        int r = k2 >> 6, d = k2 & 63;
        float v = (r < 64) ? Wlin2[r * 64 + d] : Wself2[(r - 64) * 64 + d];
        wb2[k2] = f2bf(v);
      }
    }
  }
}

// blocks [0,mblocks): gemm1 (x f32, converted in-register) -> y1 bf16 slabs + s1 bf16.
// blocks [mblocks,...): count edges per segment + rank tmp[e] (R8-proven fusion).
__global__ __launch_bounds__(256) void k_countgemm(
    const int* __restrict__ node_out, const int* __restrict__ rel,
    int* __restrict__ cnt, int* __restrict__ tmp, int E, int R,
    const float* __restrict__ xf, int M, const unsigned short* __restrict__ Wb,
    unsigned short* __restrict__ outLinB, unsigned short* __restrict__ outSelf,
    int mblocks) {
  if ((int)blockIdx.x < mblocks) {
    int m0 = blockIdx.x * 64;
    int wid = threadIdx.x >> 6;
    int lane = threadIdx.x & 63;
    int mrow = m0 + wid * 16 + (lane & 15);
    int mload = (mrow < M) ? mrow : (M - 1);
    const float* arow = xf + (size_t)mload * 64 + 8 * (lane >> 4);
    float4 af0 = *(const float4*)(arow);
    float4 af1 = *(const float4*)(arow + 4);
    float4 af2 = *(const float4*)(arow + 32);
    float4 af3 = *(const float4*)(arow + 36);
    bf16x8 a0, a1;
    a0[0] = (short)f2bf(af0.x); a0[1] = (short)f2bf(af0.y);
    a0[2] = (short)f2bf(af0.z); a0[3] = (short)f2bf(af0.w);
    a0[4] = (short)f2bf(af1.x); a0[5] = (short)f2bf(af1.y);
    a0[6] = (short)f2bf(af1.z); a0[7] = (short)f2bf(af1.w);
    a1[0] = (short)f2bf(af2.x); a1[1] = (short)f2bf(af2.y);
    a1[2] = (short)f2bf(af2.z); a1[3] = (short)f2bf(af2.w);
    a1[4] = (short)f2bf(af3.x); a1[5] = (short)f2bf(af3.y);
    a1[6] = (short)f2bf(af3.z); a1[7] = (short)f2bf(af3.w);
    int rbase = m0 + wid * 16 + ((lane >> 4) << 2);
    int cbase = lane & 15;
    for (int slab = 0; slab <= R; ++slab) {
      const unsigned short* wrow = Wb + ((size_t)slab * 64 + (lane & 15)) * 64 + 8 * (lane >> 4);
      unsigned short* op = (slab < R) ? (outLinB + (size_t)slab * M * 64) : outSelf;
      #pragma unroll
      for (int nt = 0; nt < 4; ++nt) {
        bf16x8 b0 = *(const bf16x8*)(wrow + nt * 16 * 64);
        bf16x8 b1 = *(const bf16x8*)(wrow + nt * 16 * 64 + 32);
        f32x4 c = {};
        c = __builtin_amdgcn_mfma_f32_16x16x32_bf16(a0, b0, c, 0, 0, 0);
        c = __builtin_amdgcn_mfma_f32_16x16x32_bf16(a1, b1, c, 0, 0, 0);
        int col = nt * 16 + cbase;
        #pragma unroll
        for (int rg = 0; rg < 4; ++rg) {
          int grow = rbase + rg;
          if (grow < M) op[(size_t)grow * 64 + col] = f2bf(c[rg]);
        }
      }
    }
  } else {
    int i = ((int)blockIdx.x - mblocks) * 256 + threadIdx.x;
    int stride = COUNT_BLOCKS * 256;
    for (int e = i; e < E; e += stride) {
      int seg = node_out[e] * R + rel[e];
      tmp[e] = atomicAdd(&cnt[seg], 1);
    }
  }
}

__global__ __launch_bounds__(256) void k_scan1(const int* __restrict__ cnt,
                                               int* __restrict__ bsum, int NR) {
  __shared__ int red[256];
  int tid = threadIdx.x;
  int base = blockIdx.x * SCAN_CHUNK;
  int s = 0;
  for (int i = tid; i < SCAN_CHUNK; i += 256) {
    int idx = base + i;
    if (idx < NR) s += cnt[idx];
  }
  red[tid] = s;
  __syncthreads();
  for (int off = 128; off > 0; off >>= 1) {
    if (tid < off) red[tid] += red[tid + off];
    __syncthreads();
  }
  if (tid == 0) bsum[blockIdx.x] = red[0];
}

__global__ void k_scan2(const int* __restrict__ bsum, int* __restrict__ bpre,
                        int* __restrict__ rowptr_end, int NB) {
  int lane = threadIdx.x;
  int carry = 0;
  for (int base = 0; base < NB; base += 64) {
    int i = base + lane;
    int v = (i < NB) ? bsum[i] : 0;
    int incl = v;
    #pragma unroll
    for (int off = 1; off < 64; off <<= 1) {
      int u = __shfl_up(incl, off);
      if (lane >= off) incl += u;
    }
    if (i < NB) bpre[i] = carry + incl - v;
    carry += __shfl(incl, 63);
  }
  if (lane == 0) *rowptr_end = carry;
}

// rowptr (n-major) + descT (s-major: descT[r*N+n] = start | cnt<<20)
__global__ __launch_bounds__(256) void k_scan3(const int* __restrict__ cnt,
                                               const int* __restrict__ bpre,
                                               int* __restrict__ rowptr,
                                               unsigned* __restrict__ descT,
                                               int NR, int R, int Nn) {
  __shared__ int wtot[4];
  int tid = threadIdx.x, lane = tid & 63, wid = tid >> 6;
  int base = blockIdx.x * SCAN_CHUNK + tid * 16;
  int v[16];
  int t = 0;
  #pragma unroll
  for (int i = 0; i < 16; i++) {
    int idx = base + i;
    v[i] = (idx < NR) ? cnt[idx] : 0;
    t += v[i];
  }
  int incl = t;
  #pragma unroll
  for (int off = 1; off < 64; off <<= 1) {
    int u = __shfl_up(incl, off);
    if (lane >= off) incl += u;
  }
  if (lane == 63) wtot[wid] = incl;
  __syncthreads();
  int woff = 0;
  for (int w = 0; w < wid; w++) woff += wtot[w];
  int start = bpre[blockIdx.x] + woff + incl - t;
  #pragma unroll
  for (int i = 0; i < 16; i++) {
    int idx = base + i;
    if (idx < NR) {
      rowptr[idx] = start;
      int n = (int)((unsigned)idx / (unsigned)R);
      int r = idx - n * R;
      descT[(size_t)r * Nn + n] = (unsigned)start | ((unsigned)v[i] << 20);
    }
    start += v[i];
  }
}

// placement, no atomics, 4B payload: ep4[rowptr[seg]+tmp[e]] = src | bf16(raw w)<<16
__global__ void k_place(const float* __restrict__ w, const int* __restrict__ node_out,
                        const int* __restrict__ node_in, const int* __restrict__ rel,
                        const int* __restrict__ rowptr, const int* __restrict__ tmp,
                        unsigned* __restrict__ ep4, int E, int R) {
  int i = blockIdx.x * blockDim.x + threadIdx.x;
  int stride = gridDim.x * blockDim.x;
  for (int e = i; e < E; e += stride) {
    int seg = node_out[e] * R + rel[e];
    int pos = rowptr[seg] + tmp[e];
    ep4[pos] = (unsigned)node_in[e] | ((unsigned)f2bf(w[e]) << 16);
  }
}

// layer1 gather: per-node walk over R segments of y1; single-pass inline-d norm.
// h_pre[n,c] = s1[n,c] + sum_r (1/d_r) sum_e w_e * y1[r*N+src_e, c]  (bf16 out) + stats
__global__ __launch_bounds__(256) void k_gather1(
    const int* __restrict__ rowptr, const unsigned* __restrict__ ep4,
    const unsigned short* __restrict__ y1, const unsigned short* __restrict__ s1,
    unsigned short* __restrict__ h_pre, float* __restrict__ part, int N, int R) {
  int lane = threadIdx.x & 63;
  int wid = threadIdx.x >> 6;
  int l16 = lane & 15;
  int lg = lane >> 4;
  int c0 = l16 * 4;
  int grp = blockIdx.x * 16 + wid * 4 + lg;
  int ngrp = gridDim.x * 16;
  float lsum[4] = {0.f, 0.f, 0.f, 0.f}, lsq[4] = {0.f, 0.f, 0.f, 0.f};
  for (int n = grp; n < N; n += ngrp) {
    int segbase = n * R;
    int k = rowptr[segbase];
    float t0 = 0.f, t1 = 0.f, t2 = 0.f, t3 = 0.f;
    for (int r = 0; r < R; r++) {
      int k1 = rowptr[segbase + r + 1];
      if (k < k1) {
        const unsigned short* yb = y1 + (size_t)r * N * 64;
        float a0 = 0.f, a1 = 0.f, a2 = 0.f, a3 = 0.f, d = 0.f;
        for (; k + 1 < k1; k += 2) {
          unsigned pA = ep4[k], pB = ep4[k + 1];
          ushort4 uA = *(const ushort4*)&yb[(size_t)(pA & 0xFFFFu) * 64 + c0];
          ushort4 uB = *(const ushort4*)&yb[(size_t)(pB & 0xFFFFu) * 64 + c0];
          float wA = bf2f((unsigned short)(pA >> 16));
          float wB = bf2f((unsigned short)(pB >> 16));
          d += wA + wB;
          a0 = fmaf(wA, bf2f(uA.x), a0); a1 = fmaf(wA, bf2f(uA.y), a1);
          a2 = fmaf(wA, bf2f(uA.z), a2); a3 = fmaf(wA, bf2f(uA.w), a3);
          a0 = fmaf(wB, bf2f(uB.x), a0); a1 = fmaf(wB, bf2f(uB.y), a1);
          a2 = fmaf(wB, bf2f(uB.z), a2); a3 = fmaf(wB, bf2f(uB.w), a3);
        }
        if (k < k1) {
          unsigned p = ep4[k];
          float w = bf2f((unsigned short)(p >> 16));
          ushort4 u = *(const ushort4*)&yb[(size_t)(p & 0xFFFFu) * 64 + c0];
          d += w;
          a0 = fmaf(w, bf2f(u.x), a0); a1 = fmaf(w, bf2f(u.y), a1);
          a2 = fmaf(w, bf2f(u.z), a2); a3 = fmaf(w, bf2f(u.w), a3);
        }
        if (d != 0.f) {
          float inv = 1.f / d;
          t0 = fmaf(a0, inv, t0); t1 = fmaf(a1, inv, t1);
          t2 = fmaf(a2, inv, t2); t3 = fmaf(a3, inv, t3);
        }
        k = k1;
      }
    }
    ushort4 su = *(const ushort4*)&s1[(size_t)n * 64 + c0];
    float v0 = t0 + bf2f(su.x), v1 = t1 + bf2f(su.y);
    float v2 = t2 + bf2f(su.z), v3 = t3 + bf2f(su.w);
    ushort4 o; o.x = f2bf(v0); o.y = f2bf(v1); o.z = f2bf(v2); o.w = f2bf(v3);
    *(ushort4*)&h_pre[(size_t)n * 64 + c0] = o;
    lsum[0] += v0; lsq[0] += v0 * v0;
    lsum[1] += v1; lsq[1] += v1 * v1;
    lsum[2] += v2; lsq[2] += v2 * v2;
    lsum[3] += v3; lsq[3] += v3 * v3;
  }
  __shared__ float sp[16][64], sq[16][64];
  int g = wid * 4 + lg;
  #pragma unroll
  for (int i = 0; i < 4; i++) { sp[g][c0 + i] = lsum[i]; sq[g][c0 + i] = lsq[i]; }
  __syncthreads();
  if (threadIdx.x < 64) {
    int j = threadIdx.x;
    float s = 0.f, q = 0.f;
    #pragma unroll
    for (int gg = 0; gg < 16; gg++) { s += sp[gg][j]; q += sq[gg][j]; }
    part[(size_t)blockIdx.x * 128 + j] = s;
    part[(size_t)blockIdx.x * 128 + 64 + j] = q;
  }
}

// gemm2 with fused bn+relu on A (h_pre) using ss1 -> z bf16, s2 bf16.
__global__ __launch_bounds__(256) void k_gemm2bn(
    const unsigned short* __restrict__ hp, int M,
    const unsigned short* __restrict__ Wb, int nslab,
    const float* __restrict__ ss,
    unsigned short* __restrict__ outLinB, unsigned short* __restrict__ outSelf) {
  __shared__ float sss[128];
  if (threadIdx.x < 128) sss[threadIdx.x] = ss[threadIdx.x];
  __syncthreads();
  int m0 = blockIdx.x * 64;
  int wid = threadIdx.x >> 6;
  int lane = threadIdx.x & 63;
  int mrow = m0 + wid * 16 + (lane & 15);
  int mload = (mrow < M) ? mrow : (M - 1);
  int cb = 8 * (lane >> 4);
  const unsigned short* arow = hp + (size_t)mload * 64 + cb;
  ushort4 u0 = *(const ushort4*)(arow);
  ushort4 u1 = *(const ushort4*)(arow + 4);
  ushort4 u2 = *(const ushort4*)(arow + 32);
  ushort4 u3 = *(const ushort4*)(arow + 36);
  bf16x8 a0, a1;
  #pragma unroll
  for (int j = 0; j < 4; j++) {
    unsigned short uu0 = (&u0.x)[j], uu1 = (&u1.x)[j], uu2 = (&u2.x)[j], uu3 = (&u3.x)[j];
    a0[j]     = (short)f2bf(fmaxf(fmaf(bf2f(uu0), sss[cb + j],      sss[64 + cb + j]), 0.f));
    a0[j + 4] = (short)f2bf(fmaxf(fmaf(bf2f(uu1), sss[cb + 4 + j],  sss[64 + cb + 4 + j]), 0.f));
    a1[j]     = (short)f2bf(fmaxf(fmaf(bf2f(uu2), sss[cb + 32 + j], sss[64 + cb + 32 + j]), 0.f));
    a1[j + 4] = (short)f2bf(fmaxf(fmaf(bf2f(uu3), sss[cb + 36 + j], sss[64 + cb + 36 + j]), 0.f));
  }
  int rbase = m0 + wid * 16 + ((lane >> 4) << 2);
  int cbase = lane & 15;
  for (int slab = 0; slab <= nslab; ++slab) {
    const unsigned short* wrow = Wb + ((size_t)slab * 64 + (lane & 15)) * 64 + 8 * (lane >> 4);
    unsigned short* op = (slab < nslab) ? (outLinB + (size_t)slab * M * 64) : outSelf;
    #pragma unroll
    for (int nt = 0; nt < 4; ++nt) {
      bf16x8 b0 = *(const bf16x8*)(wrow + nt * 16 * 64);
      bf16x8 b1 = *(const bf16x8*)(wrow + nt * 16 * 64 + 32);
      f32x4 c = {};
      c = __builtin_amdgcn_mfma_f32_16x16x32_bf16(a0, b0, c, 0, 0, 0);
      c = __builtin_amdgcn_mfma_f32_16x16x32_bf16(a1, b1, c, 0, 0, 0);
      int col = nt * 16 + cbase;
      #pragma unroll
      for (int rg = 0; rg < 4; ++rg) {
        int grow = rbase + rg;
        if (grow < M) op[(size_t)grow * 64 + col] = f2bf(c[rg]);
      }
    }
  }
}

// layer2 stats: s-major, descT single load, inline 1/d scaling.
__global__ __launch_bounds__(256) void k_gather2_stats(
    const unsigned* __restrict__ descT, const unsigned* __restrict__ ep4,
    const unsigned short* __restrict__ z, const unsigned short* __restrict__ s2,
    float* __restrict__ part, int N, int R) {
  int lane = threadIdx.x & 63;
  int wid = threadIdx.x >> 6;
  int l16 = lane & 15;
  int lg = lane >> 4;
  int c0 = l16 * 4;
  int grp = blockIdx.x * 16 + wid * 4 + lg;
  int ngrp = gridDim.x * 16;
  int NR = N * R;
  float lsum[4] = {0.f, 0.f, 0.f, 0.f}, lsq[4] = {0.f, 0.f, 0.f, 0.f};
  for (int s = grp; s < NR; s += ngrp) {
    unsigned r = (unsigned)s / (unsigned)N;
    int n = s - (int)r * N;
    unsigned desc = descT[s];
    int k = (int)(desc & 0xFFFFFu);
    int cnt = (int)(desc >> 20);
    int k1 = k + cnt;
    float a0 = 0.f, a1 = 0.f, a2 = 0.f, a3 = 0.f, d = 0.f;
    for (; k + 1 < k1; k += 2) {
      unsigned pA = ep4[k], pB = ep4[k + 1];
      ushort4 uA = *(const ushort4*)&z[(size_t)(pA & 0xFFFFu) * 64 + c0];
      ushort4 uB = *(const ushort4*)&z[(size_t)(pB & 0xFFFFu) * 64 + c0];
      float wA = bf2f((unsigned short)(pA >> 16));
      float wB = bf2f((unsigned short)(pB >> 16));
      d += wA + wB;
      a0 = fmaf(wA, bf2f(uA.x), a0); a1 = fmaf(wA, bf2f(uA.y), a1);
      a2 = fmaf(wA, bf2f(uA.z), a2); a3 = fmaf(wA, bf2f(uA.w), a3);
      a0 = fmaf(wB, bf2f(uB.x), a0); a1 = fmaf(wB, bf2f(uB.y), a1);
      a2 = fmaf(wB, bf2f(uB.z), a2); a3 = fmaf(wB, bf2f(uB.w), a3);
    }
    if (k < k1) {
      unsigned p = ep4[k];
      float w = bf2f((unsigned short)(p >> 16));
      ushort4 u = *(const ushort4*)&z[(size_t)(p & 0xFFFFu) * 64 + c0];
      d += w;
      a0 = fmaf(w, bf2f(u.x), a0); a1 = fmaf(w, bf2f(u.y), a1);
      a2 = fmaf(w, bf2f(u.z), a2); a3 = fmaf(w, bf2f(u.w), a3);
    }
    if (d != 0.f) {
      float inv = 1.f / d;
      a0 *= inv; a1 *= inv; a2 *= inv; a3 *= inv;
    }
    ushort4 su = *(const ushort4*)&s2[(size_t)n * 64 + c0];
    float v0 = a0 + bf2f(su.x), v1 = a1 + bf2f(su.y);
    float v2 = a2 + bf2f(su.z), v3 = a3 + bf2f(su.w);
    lsum[0] += v0; lsq[0] += v0 * v0;
    lsum[1] += v1; lsq[1] += v1 * v1;
    lsum[2] += v2; lsq[2] += v2 * v2;
    lsum[3] += v3; lsq[3] += v3 * v3;
  }
  __shared__ float sp[16][64], sq[16][64];
  int g = wid * 4 + lg;
  #pragma unroll
  for (int i = 0; i < 4; i++) { sp[g][c0 + i] = lsum[i]; sq[g][c0 + i] = lsq[i]; }
  __syncthreads();
  if (threadIdx.x < 64) {
    int j = threadIdx.x;
    float s = 0.f, q = 0.f;
    #pragma unroll
    for (int gg = 0; gg < 16; gg++) { s += sp[gg][j]; q += sq[gg][j]; }
    part[(size_t)blockIdx.x * 128 + j] = s;
    part[(size_t)blockIdx.x * 128 + 64 + j] = q;
  }
}

// layer2 write: s-major, descT, inline 1/d, BN+relu, contiguous f32 to d_out.
__global__ __launch_bounds__(256) void k_gather2_write(
    const unsigned* __restrict__ descT, const unsigned* __restrict__ ep4,
    const unsigned short* __restrict__ z, const unsigned short* __restrict__ s2,
    const float* __restrict__ ss, float* __restrict__ out, int N, int R) {
  int lane = threadIdx.x & 63;
  int wid = threadIdx.x >> 6;
  int l16 = lane & 15;
  int lg = lane >> 4;
  int c0 = l16 * 4;
  float sc0 = ss[c0], sc1 = ss[c0 + 1], sc2 = ss[c0 + 2], sc3 = ss[c0 + 3];
  float sh0 = ss[64 + c0], sh1 = ss[64 + c0 + 1], sh2 = ss[64 + c0 + 2], sh3 = ss[64 + c0 + 3];
  int grp = blockIdx.x * 16 + wid * 4 + lg;
  int ngrp = gridDim.x * 16;
  int NR = N * R;
  for (int s = grp; s < NR; s += ngrp) {
    unsigned r = (unsigned)s / (unsigned)N;
    int n = s - (int)r * N;
    unsigned desc = descT[s];
    int k = (int)(desc & 0xFFFFFu);
    int cnt = (int)(desc >> 20);
    int k1 = k + cnt;
    float a0 = 0.f, a1 = 0.f, a2 = 0.f, a3 = 0.f, d = 0.f;
    for (; k + 1 < k1; k += 2) {
      unsigned pA = ep4[k], pB = ep4[k + 1];
      ushort4 uA = *(const ushort4*)&z[(size_t)(pA & 0xFFFFu) * 64 + c0];
      ushort4 uB = *(const ushort4*)&z[(size_t)(pB & 0xFFFFu) * 64 + c0];
      float wA = bf2f((unsigned short)(pA >> 16));
      float wB = bf2f((unsigned short)(pB >> 16));
      d += wA + wB;
      a0 = fmaf(wA, bf2f(uA.x), a0); a1 = fmaf(wA, bf2f(uA.y), a1);
      a2 = fmaf(wA, bf2f(uA.z), a2); a3 = fmaf(wA, bf2f(uA.w), a3);
      a0 = fmaf(wB, bf2f(uB.x), a0); a1 = fmaf(wB, bf2f(uB.y), a1);
      a2 = fmaf(wB, bf2f(uB.z), a2); a3 = fmaf(wB, bf2f(uB.w), a3);
    }
    if (k < k1) {
      unsigned p = ep4[k];
      float w = bf2f((unsigned short)(p >> 16));
      ushort4 u = *(const ushort4*)&z[(size_t)(p & 0xFFFFu) * 64 + c0];
      d += w;
      a0 = fmaf(w, bf2f(u.x), a0); a1 = fmaf(w, bf2f(u.y), a1);
      a2 = fmaf(w, bf2f(u.z), a2); a3 = fmaf(w, bf2f(u.w), a3);
    }
    if (d != 0.f) {
      float inv = 1.f / d;
      a0 *= inv; a1 *= inv; a2 *= inv; a3 *= inv;
    }
    ushort4 su = *(const ushort4*)&s2[(size_t)n * 64 + c0];
    float v0 = fmaxf(fmaf(a0 + bf2f(su.x), sc0, sh0), 0.f);
    float v1 = fmaxf(fmaf(a1 + bf2f(su.y), sc1, sh1), 0.f);
    float v2 = fmaxf(fmaf(a2 + bf2f(su.z), sc2, sh2), 0.f);
    float v3 = fmaxf(fmaf(a3 + bf2f(su.w), sc3, sh3), 0.f);
    *(float4*)&out[(size_t)s * 64 + c0] = make_float4(v0, v1, v2, v3);
  }
}

// stage-1 reduce: part[P][128] -> part2[RED_BLOCKS][128]
__global__ __launch_bounds__(256) void k_red1(const float* __restrict__ part,
                                              float* __restrict__ part2, int P) {
  int j = threadIdx.x & 127;
  int g = threadIdx.x >> 7;
  int rows = (P + RED_BLOCKS - 1) / RED_BLOCKS;
  int base = blockIdx.x * rows;
  float acc = 0.f;
  for (int i = g; i < rows; i += 2) {
    int idx = base + i;
    if (idx < P) acc += part[(size_t)idx * 128 + j];
  }
  __shared__ float red[2][128];
  red[g][j] = acc;
  __syncthreads();
  if (threadIdx.x < 128) part2[(size_t)blockIdx.x * 128 + j] = red[0][j] + red[1][j];
}

__global__ __launch_bounds__(1024) void k_bnstats(
    const float* __restrict__ part, int P, float M,
    const float* __restrict__ gamma, const float* __restrict__ beta,
    float* __restrict__ ss) {
  __shared__ float red[1024];
  int tid = threadIdx.x;
  int j = tid & 127;
  int g = tid >> 7;
  float acc = 0.f;
  for (int i = g; i < P; i += 8) acc += part[(size_t)i * 128 + j];
  red[tid] = acc;
  __syncthreads();
  if (tid < 128) {
    float s = 0.f;
    for (int gg = 0; gg < 8; gg++) s += red[gg * 128 + tid];
    red[tid] = s;
  }
  __syncthreads();
  if (tid < 64) {
    float s = red[tid], q = red[64 + tid];
    float mean = s / M;
    float var = q / M - mean * mean;
    float sc = gamma[tid] / sqrtf(var + 1e-5f);
    ss[tid] = sc;
    ss[64 + tid] = beta[tid] - mean * sc;
  }
}

extern "C" void kernel_launch(void* const* d_in, const int* in_sizes, int n_in,
                              void* d_out, int out_size, void* d_ws, size_t ws_size,
                              hipStream_t stream) {
  const float* x        = (const float*)d_in[0];
  const float* edge_w   = (const float*)d_in[1];
  const float* W_lin1   = (const float*)d_in[2];
  const float* W_self1  = (const float*)d_in[4];
  const float* gamma1   = (const float*)d_in[6];
  const float* beta1    = (const float*)d_in[7];
  const float* W_lin2   = (const float*)d_in[8];
  const float* W_self2  = (const float*)d_in[10];
  const float* gamma2   = (const float*)d_in[12];
  const float* beta2    = (const float*)d_in[13];
  const int* node_in    = (const int*)d_in[14];
  const int* node_out   = (const int*)d_in[15];
  const int* relation   = (const int*)d_in[16];

  int N = in_sizes[0] / 64;           // 50000
  int E = in_sizes[1];                // 800000
  int R = in_sizes[2] / (64 * 64);    // 8
  int NR = N * R;
  int NB = (NR + SCAN_CHUNK - 1) / SCAN_CHUNK;

  char* p = (char*)d_ws;
  auto alloc = [&](size_t bytes) { char* r = p; p += (bytes + 255) & ~(size_t)255; return r; };
  int* cnt      = (int*)alloc(4ull * NR);
  int* rowptr   = (int*)alloc(4ull * (NR + 1));
  unsigned* descT = (unsigned*)alloc(4ull * NR);
  int* tmp      = (int*)alloc(4ull * E);
  int* bsum     = (int*)alloc(4ull * NB);
  int* bpre     = (int*)alloc(4ull * NB);
  unsigned* ep4 = (unsigned*)alloc(4ull * E);
  unsigned short* wb1 = (unsigned short*)alloc(2ull * (R + 1) * 64 * 64);
  unsigned short* wb2 = (unsigned short*)alloc(2ull * 2 * 64 * 64);
  unsigned short* s1    = (unsigned short*)alloc(2ull * N * 64);
  unsigned short* h_pre = (unsigned short*)alloc(2ull * N * 64);
  unsigned short* z     = (unsigned short*)alloc(2ull * N * 64);
  unsigned short* s2    = (unsigned short*)alloc(2ull * N * 64);
  float* part   = (float*)alloc(4ull * GATHER_GRID * 128);
  float* part2  = (float*)alloc(4ull * RED_BLOCKS * 128);
  float* ss1    = (float*)alloc(4ull * 128);
  float* ss2    = (float*)alloc(4ull * 128);

  // d_out scratch: y1 bf16 [0, 51.2MB) — dead before gather2_write rewrites d_out.
  unsigned short* y1 = (unsigned short*)d_out;

  int mblocks = (N + 63) / 64;

  k_zeropack<<<ZERO_BLOCKS + PACK_BLOCKS, 256, 0, stream>>>(
      cnt, NR, R, W_lin1, W_self1, W_lin2, W_self2, wb1, wb2);
  k_countgemm<<<mblocks + COUNT_BLOCKS, 256, 0, stream>>>(
      node_out, relation, cnt, tmp, E, R, x, N, wb1, y1, s1, mblocks);
  k_scan1<<<NB, 256, 0, stream>>>(cnt, bsum, NR);
  k_scan2<<<1, 64, 0, stream>>>(bsum, bpre, &rowptr[NR], NB);
  k_scan3<<<NB, 256, 0, stream>>>(cnt, bpre, rowptr, descT, NR, R, N);
  k_place<<<PLACE_BLOCKS, 256, 0, stream>>>(
      edge_w, node_out, node_in, relation, rowptr, tmp, ep4, E, R);

  // layer 1 gather (+stats, inline-d norm)
  k_gather1<<<GATHER_GRID, 256, 0, stream>>>(rowptr, ep4, y1, s1, h_pre, part, N, R);
  k_red1<<<RED_BLOCKS, 256, 0, stream>>>(part, part2, GATHER_GRID);
  k_bnstats<<<1, 1024, 0, stream>>>(part2, RED_BLOCKS, (float)N, gamma1, beta1, ss1);

  // layer 2: gemm (bn+relu fused on A) -> stats -> write
  k_gemm2bn<<<mblocks, 256, 0, stream>>>(h_pre, N, wb2, 1, ss1, z, s2);
  k_gather2_stats<<<GATHER_GRID, 256, 0, stream>>>(descT, ep4, z, s2, part, N, R);
  k_red1<<<RED_BLOCKS, 256, 0, stream>>>(part, part2, GATHER_GRID);
  k_bnstats<<<1, 1024, 0, stream>>>(part2, RED_BLOCKS, (float)N * R, gamma2, beta2, ss2);
  k_gather2_write<<<GATHER_GRID, 256, 0, stream>>>(descT, ep4, z, s2, ss2, (float*)d_out, N, R);
}

// Round 14
// 239.355 us; speedup vs baseline: 1.1925x; 1.0699x over previous
//
#include <hip/hip_runtime.h>

// relationalGraphStack — round 13
// vs R12 (256.1us record): second segment walk (k_gather2_write, ~40us
// L3-latency-bound) eliminated. k_gather2_statsave stores pre-activation bf16
// into the low half of each output row's own f32 slot in d_out; streaming
// k_bnrelu_inplace expands bf16 -> BN+relu -> f32 per row (wave-local
// read-before-write). Everything else identical to R12.

#define GATHER_GRID 2048
#define SCAN_CHUNK 4096
#define RED_BLOCKS 64
#define ZERO_BLOCKS 256
#define PACK_BLOCKS 16
#define COUNT_BLOCKS 2048
#define PLACE_BLOCKS 1024

typedef short bf16x8 __attribute__((ext_vector_type(8)));
typedef float f32x4 __attribute__((ext_vector_type(4)));

static __device__ __forceinline__ float bf2f(unsigned short u) {
  return __uint_as_float(((unsigned)u) << 16);
}
static __device__ __forceinline__ unsigned short f2bf(float f) {
  unsigned u = __float_as_uint(f);
  u += 0x7FFFu + ((u >> 16) & 1u);  // round to nearest even
  return (unsigned short)(u >> 16);
}

// zero cnt + pack weights (9-slab wb1; wb2 = [Wlin2; Wself2]).
__global__ void k_zeropack(int* __restrict__ cnt, int NR, int R,
                           const float* __restrict__ Wlin1, const float* __restrict__ Wself1,
                           const float* __restrict__ Wlin2, const float* __restrict__ Wself2,
                           unsigned short* __restrict__ wb1, unsigned short* __restrict__ wb2) {
  if (blockIdx.x < ZERO_BLOCKS) {
    int i = blockIdx.x * 256 + threadIdx.x;
    int stride = ZERO_BLOCKS * 256;
    for (int k = i; k < NR; k += stride) cnt[k] = 0;
  } else {
    int i = (blockIdx.x - ZERO_BLOCKS) * 256 + threadIdx.x;
    int stride = PACK_BLOCKS * 256;
    int n1 = (R + 1) * 64 * 64;
    int n2 = 2 * 64 * 64;
    for (int k = i; k < n1 + n2; k += stride) {
      if (k < n1) {
        int r = k >> 6, d = k & 63;
        float v;
        if (r < R * 64) {
          int s = r >> 6, j = r & 63;
          v = Wlin1[j * (R * 64) + s * 64 + d];
        } else {
          v = Wself1[(r - R * 64) * 64 + d];
        }
        wb1[k] = f2bf(v);
      } else {
        int k2 = k - n1;
        int r = k2 >> 6, d = k2 & 63;
        float v = (r < 64) ? Wlin2[r * 64 + d] : Wself2[(r - 64) * 64 + d];
        wb2[k2] = f2bf(v);
      }
    }
  }
}

// blocks [0,mblocks): gemm1 -> y1 bf16 slabs + s1 bf16.  blocks [mblocks,...):
// count edges per segment + rank tmp[e].
__global__ __launch_bounds__(256) void k_countgemm(
    const int* __restrict__ node_out, const int* __restrict__ rel,
    int* __restrict__ cnt, int* __restrict__ tmp, int E, int R,
    const float* __restrict__ xf, int M, const unsigned short* __restrict__ Wb,
    unsigned short* __restrict__ outLinB, unsigned short* __restrict__ outSelf,
    int mblocks) {
  if ((int)blockIdx.x < mblocks) {
    int m0 = blockIdx.x * 64;
    int wid = threadIdx.x >> 6;
    int lane = threadIdx.x & 63;
    int mrow = m0 + wid * 16 + (lane & 15);
    int mload = (mrow < M) ? mrow : (M - 1);
    const float* arow = xf + (size_t)mload * 64 + 8 * (lane >> 4);
    float4 af0 = *(const float4*)(arow);
    float4 af1 = *(const float4*)(arow + 4);
    float4 af2 = *(const float4*)(arow + 32);
    float4 af3 = *(const float4*)(arow + 36);
    bf16x8 a0, a1;
    a0[0] = (short)f2bf(af0.x); a0[1] = (short)f2bf(af0.y);
    a0[2] = (short)f2bf(af0.z); a0[3] = (short)f2bf(af0.w);
    a0[4] = (short)f2bf(af1.x); a0[5] = (short)f2bf(af1.y);
    a0[6] = (short)f2bf(af1.z); a0[7] = (short)f2bf(af1.w);
    a1[0] = (short)f2bf(af2.x); a1[1] = (short)f2bf(af2.y);
    a1[2] = (short)f2bf(af2.z); a1[3] = (short)f2bf(af2.w);
    a1[4] = (short)f2bf(af3.x); a1[5] = (short)f2bf(af3.y);
    a1[6] = (short)f2bf(af3.z); a1[7] = (short)f2bf(af3.w);
    int rbase = m0 + wid * 16 + ((lane >> 4) << 2);
    int cbase = lane & 15;
    for (int slab = 0; slab <= R; ++slab) {
      const unsigned short* wrow = Wb + ((size_t)slab * 64 + (lane & 15)) * 64 + 8 * (lane >> 4);
      unsigned short* op = (slab < R) ? (outLinB + (size_t)slab * M * 64) : outSelf;
      #pragma unroll
      for (int nt = 0; nt < 4; ++nt) {
        bf16x8 b0 = *(const bf16x8*)(wrow + nt * 16 * 64);
        bf16x8 b1 = *(const bf16x8*)(wrow + nt * 16 * 64 + 32);
        f32x4 c = {};
        c = __builtin_amdgcn_mfma_f32_16x16x32_bf16(a0, b0, c, 0, 0, 0);
        c = __builtin_amdgcn_mfma_f32_16x16x32_bf16(a1, b1, c, 0, 0, 0);
        int col = nt * 16 + cbase;
        #pragma unroll
        for (int rg = 0; rg < 4; ++rg) {
          int grow = rbase + rg;
          if (grow < M) op[(size_t)grow * 64 + col] = f2bf(c[rg]);
        }
      }
    }
  } else {
    int i = ((int)blockIdx.x - mblocks) * 256 + threadIdx.x;
    int stride = COUNT_BLOCKS * 256;
    for (int e = i; e < E; e += stride) {
      int seg = node_out[e] * R + rel[e];
      tmp[e] = atomicAdd(&cnt[seg], 1);
    }
  }
}

__global__ __launch_bounds__(256) void k_scan1(const int* __restrict__ cnt,
                                               int* __restrict__ bsum, int NR) {
  __shared__ int red[256];
  int tid = threadIdx.x;
  int base = blockIdx.x * SCAN_CHUNK;
  int s = 0;
  for (int i = tid; i < SCAN_CHUNK; i += 256) {
    int idx = base + i;
    if (idx < NR) s += cnt[idx];
  }
  red[tid] = s;
  __syncthreads();
  for (int off = 128; off > 0; off >>= 1) {
    if (tid < off) red[tid] += red[tid + off];
    __syncthreads();
  }
  if (tid == 0) bsum[blockIdx.x] = red[0];
}

__global__ void k_scan2(const int* __restrict__ bsum, int* __restrict__ bpre,
                        int* __restrict__ rowptr_end, int NB) {
  int lane = threadIdx.x;
  int carry = 0;
  for (int base = 0; base < NB; base += 64) {
    int i = base + lane;
    int v = (i < NB) ? bsum[i] : 0;
    int incl = v;
    #pragma unroll
    for (int off = 1; off < 64; off <<= 1) {
      int u = __shfl_up(incl, off);
      if (lane >= off) incl += u;
    }
    if (i < NB) bpre[i] = carry + incl - v;
    carry += __shfl(incl, 63);
  }
  if (lane == 0) *rowptr_end = carry;
}

// rowptr (n-major) + descT (s-major: descT[r*N+n] = start | cnt<<20)
__global__ __launch_bounds__(256) void k_scan3(const int* __restrict__ cnt,
                                               const int* __restrict__ bpre,
                                               int* __restrict__ rowptr,
                                               unsigned* __restrict__ descT,
                                               int NR, int R, int Nn) {
  __shared__ int wtot[4];
  int tid = threadIdx.x, lane = tid & 63, wid = tid >> 6;
  int base = blockIdx.x * SCAN_CHUNK + tid * 16;
  int v[16];
  int t = 0;
  #pragma unroll
  for (int i = 0; i < 16; i++) {
    int idx = base + i;
    v[i] = (idx < NR) ? cnt[idx] : 0;
    t += v[i];
  }
  int incl = t;
  #pragma unroll
  for (int off = 1; off < 64; off <<= 1) {
    int u = __shfl_up(incl, off);
    if (lane >= off) incl += u;
  }
  if (lane == 63) wtot[wid] = incl;
  __syncthreads();
  int woff = 0;
  for (int w = 0; w < wid; w++) woff += wtot[w];
  int start = bpre[blockIdx.x] + woff + incl - t;
  #pragma unroll
  for (int i = 0; i < 16; i++) {
    int idx = base + i;
    if (idx < NR) {
      rowptr[idx] = start;
      int n = (int)((unsigned)idx / (unsigned)R);
      int r = idx - n * R;
      descT[(size_t)r * Nn + n] = (unsigned)start | ((unsigned)v[i] << 20);
    }
    start += v[i];
  }
}

// placement, no atomics, 4B payload: ep4[rowptr[seg]+tmp[e]] = src | bf16(raw w)<<16
__global__ void k_place(const float* __restrict__ w, const int* __restrict__ node_out,
                        const int* __restrict__ node_in, const int* __restrict__ rel,
                        const int* __restrict__ rowptr, const int* __restrict__ tmp,
                        unsigned* __restrict__ ep4, int E, int R) {
  int i = blockIdx.x * blockDim.x + threadIdx.x;
  int stride = gridDim.x * blockDim.x;
  for (int e = i; e < E; e += stride) {
    int seg = node_out[e] * R + rel[e];
    int pos = rowptr[seg] + tmp[e];
    ep4[pos] = (unsigned)node_in[e] | ((unsigned)f2bf(w[e]) << 16);
  }
}

// layer1 gather: per-node walk over R segments of y1; single-pass inline-d norm.
__global__ __launch_bounds__(256) void k_gather1(
    const int* __restrict__ rowptr, const unsigned* __restrict__ ep4,
    const unsigned short* __restrict__ y1, const unsigned short* __restrict__ s1,
    unsigned short* __restrict__ h_pre, float* __restrict__ part, int N, int R) {
  int lane = threadIdx.x & 63;
  int wid = threadIdx.x >> 6;
  int l16 = lane & 15;
  int lg = lane >> 4;
  int c0 = l16 * 4;
  int grp = blockIdx.x * 16 + wid * 4 + lg;
  int ngrp = gridDim.x * 16;
  float lsum[4] = {0.f, 0.f, 0.f, 0.f}, lsq[4] = {0.f, 0.f, 0.f, 0.f};
  for (int n = grp; n < N; n += ngrp) {
    int segbase = n * R;
    int k = rowptr[segbase];
    float t0 = 0.f, t1 = 0.f, t2 = 0.f, t3 = 0.f;
    for (int r = 0; r < R; r++) {
      int k1 = rowptr[segbase + r + 1];
      if (k < k1) {
        const unsigned short* yb = y1 + (size_t)r * N * 64;
        float a0 = 0.f, a1 = 0.f, a2 = 0.f, a3 = 0.f, d = 0.f;
        for (; k + 1 < k1; k += 2) {
          unsigned pA = ep4[k], pB = ep4[k + 1];
          ushort4 uA = *(const ushort4*)&yb[(size_t)(pA & 0xFFFFu) * 64 + c0];
          ushort4 uB = *(const ushort4*)&yb[(size_t)(pB & 0xFFFFu) * 64 + c0];
          float wA = bf2f((unsigned short)(pA >> 16));
          float wB = bf2f((unsigned short)(pB >> 16));
          d += wA + wB;
          a0 = fmaf(wA, bf2f(uA.x), a0); a1 = fmaf(wA, bf2f(uA.y), a1);
          a2 = fmaf(wA, bf2f(uA.z), a2); a3 = fmaf(wA, bf2f(uA.w), a3);
          a0 = fmaf(wB, bf2f(uB.x), a0); a1 = fmaf(wB, bf2f(uB.y), a1);
          a2 = fmaf(wB, bf2f(uB.z), a2); a3 = fmaf(wB, bf2f(uB.w), a3);
        }
        if (k < k1) {
          unsigned p = ep4[k];
          float w = bf2f((unsigned short)(p >> 16));
          ushort4 u = *(const ushort4*)&yb[(size_t)(p & 0xFFFFu) * 64 + c0];
          d += w;
          a0 = fmaf(w, bf2f(u.x), a0); a1 = fmaf(w, bf2f(u.y), a1);
          a2 = fmaf(w, bf2f(u.z), a2); a3 = fmaf(w, bf2f(u.w), a3);
        }
        if (d != 0.f) {
          float inv = 1.f / d;
          t0 = fmaf(a0, inv, t0); t1 = fmaf(a1, inv, t1);
          t2 = fmaf(a2, inv, t2); t3 = fmaf(a3, inv, t3);
        }
        k = k1;
      }
    }
    ushort4 su = *(const ushort4*)&s1[(size_t)n * 64 + c0];
    float v0 = t0 + bf2f(su.x), v1 = t1 + bf2f(su.y);
    float v2 = t2 + bf2f(su.z), v3 = t3 + bf2f(su.w);
    ushort4 o; o.x = f2bf(v0); o.y = f2bf(v1); o.z = f2bf(v2); o.w = f2bf(v3);
    *(ushort4*)&h_pre[(size_t)n * 64 + c0] = o;
    lsum[0] += v0; lsq[0] += v0 * v0;
    lsum[1] += v1; lsq[1] += v1 * v1;
    lsum[2] += v2; lsq[2] += v2 * v2;
    lsum[3] += v3; lsq[3] += v3 * v3;
  }
  __shared__ float sp[16][64], sq[16][64];
  int g = wid * 4 + lg;
  #pragma unroll
  for (int i = 0; i < 4; i++) { sp[g][c0 + i] = lsum[i]; sq[g][c0 + i] = lsq[i]; }
  __syncthreads();
  if (threadIdx.x < 64) {
    int j = threadIdx.x;
    float s = 0.f, q = 0.f;
    #pragma unroll
    for (int gg = 0; gg < 16; gg++) { s += sp[gg][j]; q += sq[gg][j]; }
    part[(size_t)blockIdx.x * 128 + j] = s;
    part[(size_t)blockIdx.x * 128 + 64 + j] = q;
  }
}

// gemm2 with fused bn+relu on A (h_pre) using ss1 -> z bf16, s2 bf16.
__global__ __launch_bounds__(256) void k_gemm2bn(
    const unsigned short* __restrict__ hp, int M,
    const unsigned short* __restrict__ Wb, int nslab,
    const float* __restrict__ ss,
    unsigned short* __restrict__ outLinB, unsigned short* __restrict__ outSelf) {
  __shared__ float sss[128];
  if (threadIdx.x < 128) sss[threadIdx.x] = ss[threadIdx.x];
  __syncthreads();
  int m0 = blockIdx.x * 64;
  int wid = threadIdx.x >> 6;
  int lane = threadIdx.x & 63;
  int mrow = m0 + wid * 16 + (lane & 15);
  int mload = (mrow < M) ? mrow : (M - 1);
  int cb = 8 * (lane >> 4);
  const unsigned short* arow = hp + (size_t)mload * 64 + cb;
  ushort4 u0 = *(const ushort4*)(arow);
  ushort4 u1 = *(const ushort4*)(arow + 4);
  ushort4 u2 = *(const ushort4*)(arow + 32);
  ushort4 u3 = *(const ushort4*)(arow + 36);
  bf16x8 a0, a1;
  #pragma unroll
  for (int j = 0; j < 4; j++) {
    unsigned short uu0 = (&u0.x)[j], uu1 = (&u1.x)[j], uu2 = (&u2.x)[j], uu3 = (&u3.x)[j];
    a0[j]     = (short)f2bf(fmaxf(fmaf(bf2f(uu0), sss[cb + j],      sss[64 + cb + j]), 0.f));
    a0[j + 4] = (short)f2bf(fmaxf(fmaf(bf2f(uu1), sss[cb + 4 + j],  sss[64 + cb + 4 + j]), 0.f));
    a1[j]     = (short)f2bf(fmaxf(fmaf(bf2f(uu2), sss[cb + 32 + j], sss[64 + cb + 32 + j]), 0.f));
    a1[j + 4] = (short)f2bf(fmaxf(fmaf(bf2f(uu3), sss[cb + 36 + j], sss[64 + cb + 36 + j]), 0.f));
  }
  int rbase = m0 + wid * 16 + ((lane >> 4) << 2);
  int cbase = lane & 15;
  for (int slab = 0; slab <= nslab; ++slab) {
    const unsigned short* wrow = Wb + ((size_t)slab * 64 + (lane & 15)) * 64 + 8 * (lane >> 4);
    unsigned short* op = (slab < nslab) ? (outLinB + (size_t)slab * M * 64) : outSelf;
    #pragma unroll
    for (int nt = 0; nt < 4; ++nt) {
      bf16x8 b0 = *(const bf16x8*)(wrow + nt * 16 * 64);
      bf16x8 b1 = *(const bf16x8*)(wrow + nt * 16 * 64 + 32);
      f32x4 c = {};
      c = __builtin_amdgcn_mfma_f32_16x16x32_bf16(a0, b0, c, 0, 0, 0);
      c = __builtin_amdgcn_mfma_f32_16x16x32_bf16(a1, b1, c, 0, 0, 0);
      int col = nt * 16 + cbase;
      #pragma unroll
      for (int rg = 0; rg < 4; ++rg) {
        int grow = rbase + rg;
        if (grow < M) op[(size_t)grow * 64 + col] = f2bf(c[rg]);
      }
    }
  }
}

// layer2 stats + SAVE pre-activation bf16 into the low half of each output
// row's own f32 slot in d_out (row s: bytes [s*256, s*256+128)).
__global__ __launch_bounds__(256) void k_gather2_statsave(
    const unsigned* __restrict__ descT, const unsigned* __restrict__ ep4,
    const unsigned short* __restrict__ z, const unsigned short* __restrict__ s2,
    float* __restrict__ part, unsigned short* __restrict__ pre, int N, int R) {
  int lane = threadIdx.x & 63;
  int wid = threadIdx.x >> 6;
  int l16 = lane & 15;
  int lg = lane >> 4;
  int c0 = l16 * 4;
  int grp = blockIdx.x * 16 + wid * 4 + lg;
  int ngrp = gridDim.x * 16;
  int NR = N * R;
  float lsum[4] = {0.f, 0.f, 0.f, 0.f}, lsq[4] = {0.f, 0.f, 0.f, 0.f};
  for (int s = grp; s < NR; s += ngrp) {
    unsigned r = (unsigned)s / (unsigned)N;
    int n = s - (int)r * N;
    unsigned desc = descT[s];
    int k = (int)(desc & 0xFFFFFu);
    int cnt = (int)(desc >> 20);
    int k1 = k + cnt;
    float a0 = 0.f, a1 = 0.f, a2 = 0.f, a3 = 0.f, d = 0.f;
    for (; k + 1 < k1; k += 2) {
      unsigned pA = ep4[k], pB = ep4[k + 1];
      ushort4 uA = *(const ushort4*)&z[(size_t)(pA & 0xFFFFu) * 64 + c0];
      ushort4 uB = *(const ushort4*)&z[(size_t)(pB & 0xFFFFu) * 64 + c0];
      float wA = bf2f((unsigned short)(pA >> 16));
      float wB = bf2f((unsigned short)(pB >> 16));
      d += wA + wB;
      a0 = fmaf(wA, bf2f(uA.x), a0); a1 = fmaf(wA, bf2f(uA.y), a1);
      a2 = fmaf(wA, bf2f(uA.z), a2); a3 = fmaf(wA, bf2f(uA.w), a3);
      a0 = fmaf(wB, bf2f(uB.x), a0); a1 = fmaf(wB, bf2f(uB.y), a1);
      a2 = fmaf(wB, bf2f(uB.z), a2); a3 = fmaf(wB, bf2f(uB.w), a3);
    }
    if (k < k1) {
      unsigned p = ep4[k];
      float w = bf2f((unsigned short)(p >> 16));
      ushort4 u = *(const ushort4*)&z[(size_t)(p & 0xFFFFu) * 64 + c0];
      d += w;
      a0 = fmaf(w, bf2f(u.x), a0); a1 = fmaf(w, bf2f(u.y), a1);
      a2 = fmaf(w, bf2f(u.z), a2); a3 = fmaf(w, bf2f(u.w), a3);
    }
    if (d != 0.f) {
      float inv = 1.f / d;
      a0 *= inv; a1 *= inv; a2 *= inv; a3 *= inv;
    }
    ushort4 su = *(const ushort4*)&s2[(size_t)n * 64 + c0];
    float v0 = a0 + bf2f(su.x), v1 = a1 + bf2f(su.y);
    float v2 = a2 + bf2f(su.z), v3 = a3 + bf2f(su.w);
    ushort4 o; o.x = f2bf(v0); o.y = f2bf(v1); o.z = f2bf(v2); o.w = f2bf(v3);
    *(ushort4*)&pre[(size_t)s * 128 + c0] = o;   // low half of row s's f32 slot
    lsum[0] += v0; lsq[0] += v0 * v0;
    lsum[1] += v1; lsq[1] += v1 * v1;
    lsum[2] += v2; lsq[2] += v2 * v2;
    lsum[3] += v3; lsq[3] += v3 * v3;
  }
  __shared__ float sp[16][64], sq[16][64];
  int g = wid * 4 + lg;
  #pragma unroll
  for (int i = 0; i < 4; i++) { sp[g][c0 + i] = lsum[i]; sq[g][c0 + i] = lsq[i]; }
  __syncthreads();
  if (threadIdx.x < 64) {
    int j = threadIdx.x;
    float s = 0.f, q = 0.f;
    #pragma unroll
    for (int gg = 0; gg < 16; gg++) { s += sp[gg][j]; q += sq[gg][j]; }
    part[(size_t)blockIdx.x * 128 + j] = s;
    part[(size_t)blockIdx.x * 128 + 64 + j] = q;
  }
}

// streaming in-place expand: row s low-half bf16 -> BN+relu -> full f32 row.
// Each 16-lane group owns one row: loads complete before stores (program order).
__global__ __launch_bounds__(256) void k_bnrelu_inplace(
    float* __restrict__ out, const float* __restrict__ ss, int NR) {
  __shared__ float sss[128];
  if (threadIdx.x < 128) sss[threadIdx.x] = ss[threadIdx.x];
  __syncthreads();
  int l16 = threadIdx.x & 15;
  int c0 = l16 * 4;
  float sc0 = sss[c0], sc1 = sss[c0 + 1], sc2 = sss[c0 + 2], sc3 = sss[c0 + 3];
  float sh0 = sss[64 + c0], sh1 = sss[64 + c0 + 1], sh2 = sss[64 + c0 + 2], sh3 = sss[64 + c0 + 3];
  int row = blockIdx.x * 16 + (threadIdx.x >> 4);
  int stride = gridDim.x * 16;
  const unsigned short* pre = (const unsigned short*)out;
  for (int s = row; s < NR; s += stride) {
    ushort4 u = *(const ushort4*)&pre[(size_t)s * 128 + c0];
    float v0 = fmaxf(fmaf(bf2f(u.x), sc0, sh0), 0.f);
    float v1 = fmaxf(fmaf(bf2f(u.y), sc1, sh1), 0.f);
    float v2 = fmaxf(fmaf(bf2f(u.z), sc2, sh2), 0.f);
    float v3 = fmaxf(fmaf(bf2f(u.w), sc3, sh3), 0.f);
    *(float4*)&out[(size_t)s * 64 + c0] = make_float4(v0, v1, v2, v3);
  }
}

// stage-1 reduce: part[P][128] -> part2[RED_BLOCKS][128]
__global__ __launch_bounds__(256) void k_red1(const float* __restrict__ part,
                                              float* __restrict__ part2, int P) {
  int j = threadIdx.x & 127;
  int g = threadIdx.x >> 7;
  int rows = (P + RED_BLOCKS - 1) / RED_BLOCKS;
  int base = blockIdx.x * rows;
  float acc = 0.f;
  for (int i = g; i < rows; i += 2) {
    int idx = base + i;
    if (idx < P) acc += part[(size_t)idx * 128 + j];
  }
  __shared__ float red[2][128];
  red[g][j] = acc;
  __syncthreads();
  if (threadIdx.x < 128) part2[(size_t)blockIdx.x * 128 + j] = red[0][j] + red[1][j];
}

__global__ __launch_bounds__(1024) void k_bnstats(
    const float* __restrict__ part, int P, float M,
    const float* __restrict__ gamma, const float* __restrict__ beta,
    float* __restrict__ ss) {
  __shared__ float red[1024];
  int tid = threadIdx.x;
  int j = tid & 127;
  int g = tid >> 7;
  float acc = 0.f;
  for (int i = g; i < P; i += 8) acc += part[(size_t)i * 128 + j];
  red[tid] = acc;
  __syncthreads();
  if (tid < 128) {
    float s = 0.f;
    for (int gg = 0; gg < 8; gg++) s += red[gg * 128 + tid];
    red[tid] = s;
  }
  __syncthreads();
  if (tid < 64) {
    float s = red[tid], q = red[64 + tid];
    float mean = s / M;
    float var = q / M - mean * mean;
    float sc = gamma[tid] / sqrtf(var + 1e-5f);
    ss[tid] = sc;
    ss[64 + tid] = beta[tid] - mean * sc;
  }
}

extern "C" void kernel_launch(void* const* d_in, const int* in_sizes, int n_in,
                              void* d_out, int out_size, void* d_ws, size_t ws_size,
                              hipStream_t stream) {
  const float* x        = (const float*)d_in[0];
  const float* edge_w   = (const float*)d_in[1];
  const float* W_lin1   = (const float*)d_in[2];
  const float* W_self1  = (const float*)d_in[4];
  const float* gamma1   = (const float*)d_in[6];
  const float* beta1    = (const float*)d_in[7];
  const float* W_lin2   = (const float*)d_in[8];
  const float* W_self2  = (const float*)d_in[10];
  const float* gamma2   = (const float*)d_in[12];
  const float* beta2    = (const float*)d_in[13];
  const int* node_in    = (const int*)d_in[14];
  const int* node_out   = (const int*)d_in[15];
  const int* relation   = (const int*)d_in[16];

  int N = in_sizes[0] / 64;           // 50000
  int E = in_sizes[1];                // 800000
  int R = in_sizes[2] / (64 * 64);    // 8
  int NR = N * R;
  int NB = (NR + SCAN_CHUNK - 1) / SCAN_CHUNK;

  char* p = (char*)d_ws;
  auto alloc = [&](size_t bytes) { char* r = p; p += (bytes + 255) & ~(size_t)255; return r; };
  int* cnt      = (int*)alloc(4ull * NR);
  int* rowptr   = (int*)alloc(4ull * (NR + 1));
  unsigned* descT = (unsigned*)alloc(4ull * NR);
  int* tmp      = (int*)alloc(4ull * E);
  int* bsum     = (int*)alloc(4ull * NB);
  int* bpre     = (int*)alloc(4ull * NB);
  unsigned* ep4 = (unsigned*)alloc(4ull * E);
  unsigned short* wb1 = (unsigned short*)alloc(2ull * (R + 1) * 64 * 64);
  unsigned short* wb2 = (unsigned short*)alloc(2ull * 2 * 64 * 64);
  unsigned short* s1    = (unsigned short*)alloc(2ull * N * 64);
  unsigned short* h_pre = (unsigned short*)alloc(2ull * N * 64);
  unsigned short* z     = (unsigned short*)alloc(2ull * N * 64);
  unsigned short* s2    = (unsigned short*)alloc(2ull * N * 64);
  float* part   = (float*)alloc(4ull * GATHER_GRID * 128);
  float* part2  = (float*)alloc(4ull * RED_BLOCKS * 128);
  float* ss1    = (float*)alloc(4ull * 128);
  float* ss2    = (float*)alloc(4ull * 128);

  // d_out scratch: y1 bf16 [0, 51.2MB) — dead before statsave writes pre rows.
  unsigned short* y1 = (unsigned short*)d_out;

  int mblocks = (N + 63) / 64;

  k_zeropack<<<ZERO_BLOCKS + PACK_BLOCKS, 256, 0, stream>>>(
      cnt, NR, R, W_lin1, W_self1, W_lin2, W_self2, wb1, wb2);
  k_countgemm<<<mblocks + COUNT_BLOCKS, 256, 0, stream>>>(
      node_out, relation, cnt, tmp, E, R, x, N, wb1, y1, s1, mblocks);
  k_scan1<<<NB, 256, 0, stream>>>(cnt, bsum, NR);
  k_scan2<<<1, 64, 0, stream>>>(bsum, bpre, &rowptr[NR], NB);
  k_scan3<<<NB, 256, 0, stream>>>(cnt, bpre, rowptr, descT, NR, R, N);
  k_place<<<PLACE_BLOCKS, 256, 0, stream>>>(
      edge_w, node_out, node_in, relation, rowptr, tmp, ep4, E, R);

  // layer 1 gather (+stats, inline-d norm)
  k_gather1<<<GATHER_GRID, 256, 0, stream>>>(rowptr, ep4, y1, s1, h_pre, part, N, R);
  k_red1<<<RED_BLOCKS, 256, 0, stream>>>(part, part2, GATHER_GRID);
  k_bnstats<<<1, 1024, 0, stream>>>(part2, RED_BLOCKS, (float)N, gamma1, beta1, ss1);

  // layer 2: gemm (bn+relu fused on A) -> statsave -> stats -> in-place bnrelu
  k_gemm2bn<<<mblocks, 256, 0, stream>>>(h_pre, N, wb2, 1, ss1, z, s2);
  k_gather2_statsave<<<GATHER_GRID, 256, 0, stream>>>(
      descT, ep4, z, s2, part, (unsigned short*)d_out, N, R);
  k_red1<<<RED_BLOCKS, 256, 0, stream>>>(part, part2, GATHER_GRID);
  k_bnstats<<<1, 1024, 0, stream>>>(part2, RED_BLOCKS, (float)N * R, gamma2, beta2, ss2);
  k_bnrelu_inplace<<<4096, 256, 0, stream>>>((float*)d_out, ss2, NR);
}